// Round 7
// baseline (255.723 us; speedup 1.0000x reference)
//
#include <hip/hip_runtime.h>

typedef unsigned short u16;
typedef unsigned int u32;
typedef __attribute__((ext_vector_type(8))) __bf16 bf8v;   // MFMA A/B operand (8 bf16)
typedef __attribute__((ext_vector_type(8))) short s8v;     // same bits, for packing
typedef __attribute__((ext_vector_type(4))) float f4v;     // MFMA C/D (16x16)

#define DEV static __device__ __forceinline__

constexpr int NQ = 12544;   // B*H*W = 16*28*28
constexpr int MM = 8192;    // memory bank rows
constexpr int PP = 784;     // H*W
constexpr float EPSF = 1e-12f;

DEV u16 f2bf(float f) {  // RNE f32 -> bf16 (inputs are finite normals)
  u32 u = __float_as_uint(f);
  return (u16)((u + 0x7FFFu + ((u >> 16) & 1u)) >> 16);
}
DEV float bf2f(u16 h) { return __uint_as_float((u32)h << 16); }

// async 16B global -> LDS (wave-uniform LDS base + lane*16B; per-lane global src)
DEV void gl2lds16(const u16* g, u16* l) {
  __builtin_amdgcn_global_load_lds(
      (const __attribute__((address_space(1))) unsigned int*)(g),
      (__attribute__((address_space(3))) unsigned int*)(l), 16, 0, 0);
}

// branchless sorted insert: keep 5 smallest in a0<=..<=a4
DEV void ins5(float v, float& a0, float& a1, float& a2, float& a3, float& a4) {
  float hi;
  hi = fmaxf(v, a0); a0 = fminf(v, a0); v = hi;
  hi = fmaxf(v, a1); a1 = fminf(v, a1); v = hi;
  hi = fmaxf(v, a2); a2 = fminf(v, a2); v = hi;
  hi = fmaxf(v, a3); a3 = fminf(v, a3); v = hi;
  a4 = fminf(v, a4);
}

// ================= fused prep: all f32->bf16 packs =================
DEV void pack_bf16_dev(const float* __restrict__ x, u16* __restrict__ y, int bid, int tid) {
  int g = bid * 256 + tid;
  const float4* px = (const float4*)x + (size_t)g * 2;
  float4 a = px[0], b = px[1];
  s8v o;
  o[0] = (short)f2bf(a.x); o[1] = (short)f2bf(a.y); o[2] = (short)f2bf(a.z); o[3] = (short)f2bf(a.w);
  o[4] = (short)f2bf(b.x); o[5] = (short)f2bf(b.y); o[6] = (short)f2bf(b.z); o[7] = (short)f2bf(b.w);
  ((s8v*)y)[g] = o;
}

// mem pack stores -2*m (exact scale in bf16); norm computed from ORIGINAL f32 m.
// MFMA with A=-2m and C-init=|m|^2 then emits d2' = |m|^2 - 2<q,m> directly.
template<int C>
DEV void pack_mem_dev(const float* __restrict__ x, u16* __restrict__ y, float* __restrict__ nrm,
                      int bid, int tid) {
  int row = bid * 4 + (tid >> 6), lane = tid & 63;
  constexpr int E = C / 64;
  const float* src = x + (size_t)row * C + lane * E;
  float s = 0.f;
  if constexpr (E == 4) {
    float4 v = *(const float4*)src;
    s = v.x * v.x + v.y * v.y + v.z * v.z + v.w * v.w;
    u32 lo = (u32)f2bf(-2.f * v.x) | ((u32)f2bf(-2.f * v.y) << 16);
    u32 hi = (u32)f2bf(-2.f * v.z) | ((u32)f2bf(-2.f * v.w) << 16);
    ((uint2*)(y + (size_t)row * C))[lane] = make_uint2(lo, hi);
  } else {
    float2 v = *(const float2*)src;
    s = v.x * v.x + v.y * v.y;
    ((u32*)(y + (size_t)row * C))[lane] = (u32)f2bf(-2.f * v.x) | ((u32)f2bf(-2.f * v.y) << 16);
  }
#pragma unroll
  for (int m = 1; m < 64; m <<= 1) s += __shfl_xor(s, m);
  if (lane == 0) nrm[row] = s;
}

template<int C>
DEV void pack_q_dev(const float* __restrict__ q, u16* __restrict__ qfb, int bid, int tid) {
  int g = bid * 256 + tid;   // [0, NQ * C/8); NQ%256==0 so cc is block-uniform
  int n = g % NQ;
  int cc = g / NQ;
  int b = n / PP, p = n % PP;
  int c0 = cc * 8;
  const float* src = q + ((size_t)b * C + c0) * PP + p;   // lanes: consecutive p -> coalesced
  s8v o;
#pragma unroll
  for (int i = 0; i < 8; ++i) o[i] = (short)f2bf(src[(size_t)i * PP]);
  ((s8v*)qfb)[((size_t)n * C + c0) >> 3] = o;
}

__global__ __launch_bounds__(256) void k_prep(
    const float* __restrict__ q2, const float* __restrict__ q3,
    const float* __restrict__ mem2, const float* __restrict__ mem3,
    const float* __restrict__ icov2, const float* __restrict__ icov3,
    u16* __restrict__ qf2b, u16* __restrict__ qf3b,
    u16* __restrict__ m2b, u16* __restrict__ m3b,
    u16* __restrict__ ic2b, u16* __restrict__ ic3b,
    float* __restrict__ mn2, float* __restrict__ mn3) {
  int bid = blockIdx.x, tid = threadIdx.x;
  if (bid < 2048)       pack_mem_dev<128>(mem2, m2b, mn2, bid, tid);
  else if (bid < 4096)  pack_mem_dev<256>(mem3, m3b, mn3, bid - 2048, tid);
  else if (bid < 4104)  pack_bf16_dev(icov2, ic2b, bid - 4096, tid);
  else if (bid < 4136)  pack_bf16_dev(icov3, ic3b, bid - 4104, tid);
  else if (bid < 4920)  pack_q_dev<128>(q2, qf2b, bid - 4136, tid);
  else                  pack_q_dev<256>(q3, qf3b, bid - 4920, tid);
}

// ================= fused distances + per-row 5 smallest d2' =================
// D = mfma(-2*mem_frag, q_frag) with C-init = |m|^2 -> acc IS d2' directly.
// K-major LDS [chunk][row]: ds_read_b128 at lane_base + kk*4096B + mb*256B
// (all-immediate offsets, conflict-free: each 8-lane phase = 128 contiguous bytes).
// qv pinned in registers via asm (R6 lesson: compiler rematerializes otherwise).
// Double-buffered; one barrier per tile.
template<int C, int NSPLIT, int WPEU>
__global__ __launch_bounds__(256, WPEU)
void k_score(const u16* __restrict__ qf, const u16* __restrict__ mem,
             const float* __restrict__ mn, float* __restrict__ kp) {
  constexpr int MT = 64, MS = MM / NSPLIT, NT = MS / MT;
  constexpr int CPR = C / 8;              // 16B chunks per mem row
  constexpr int SIT = CPR / 4;            // gl2lds iters per wave per tile
  __shared__ alignas(16) u16 Bs[2][CPR * 512];   // [chunk][row]: 512 u16 per chunk-col
  __shared__ alignas(16) float mnS[2][MT];

  const int tid = threadIdx.x, wave = tid >> 6, lane = tid & 63;
  const int l15 = lane & 15, kb = lane >> 4, g4 = (lane >> 4) << 2;
  const int rt = blockIdx.x / NSPLIT, split = blockIdx.x % NSPLIT;
  const int row0 = rt * 128, mb0 = split * MS;

  // q fragments (B operand; loop-invariant) -> registers, pinned.
  bf8v qv[2][C / 32];
#pragma unroll
  for (int cb = 0; cb < 2; ++cb)
#pragma unroll
    for (int kk = 0; kk < C / 32; ++kk)
      qv[cb][kk] = *(const bf8v*)(qf + (size_t)(row0 + wave * 32 + cb * 16 + l15) * C + ((kk * 4 + kb) << 3));
#pragma unroll
  for (int cb = 0; cb < 2; ++cb)
#pragma unroll
    for (int kk = 0; kk < C / 32; ++kk)
      asm volatile("" : "+v"(qv[cb][kk]));   // forbid rematerialization/reload

  // staging: wave stages whole chunk-columns (cp = wave + it*4); lane = mem row.
  auto STAGE = [&](int buf, int mt) {
    const u16* src = mem + (size_t)(mb0 + mt * MT + lane) * C;
    u16* dst = Bs[buf] + lane * 8;
#pragma unroll
    for (int it = 0; it < SIT; ++it) {
      int cp = wave + it * 4;
      gl2lds16(src + cp * 8, dst + cp * 512);
    }
    if (tid < 16) gl2lds16((const u16*)(mn + mb0 + mt * MT) + tid * 8, (u16*)mnS[buf] + tid * 8);
  };

  STAGE(0, 0);
  __syncthreads();   // vmcnt drained -> buf0 ready

  float t5[2][5];
#pragma unroll
  for (int cb = 0; cb < 2; ++cb)
#pragma unroll
    for (int i = 0; i < 5; ++i) t5[cb][i] = 1e30f;

  for (int mt = 0; mt < NT; ++mt) {
    const int cur = mt & 1;
    if (mt + 1 < NT) STAGE(cur ^ 1, mt + 1);   // async prefetch into other buffer

    f4v mnv[4];
#pragma unroll
    for (int mb = 0; mb < 4; ++mb) mnv[mb] = *(const f4v*)(mnS[cur] + mb * 16 + g4);

    f4v acc[4][2];   // [mb: mem 16-block][cb: q 16-block]; init = |m|^2
#pragma unroll
    for (int mb = 0; mb < 4; ++mb)
#pragma unroll
      for (int cb = 0; cb < 2; ++cb) acc[mb][cb] = mnv[mb];

    const u16* Bb = Bs[cur] + kb * 512 + l15 * 8;   // per-lane base; rest is immediates
#pragma unroll
    for (int kk = 0; kk < C / 32; ++kk) {
      bf8v mf[4];
#pragma unroll
      for (int mb = 0; mb < 4; ++mb)
        mf[mb] = *(const bf8v*)(Bb + kk * 2048 + mb * 128);
#pragma unroll
      for (int mb = 0; mb < 4; ++mb)
#pragma unroll
        for (int cb = 0; cb < 2; ++cb)
          acc[mb][cb] = __builtin_amdgcn_mfma_f32_16x16x32_bf16(mf[mb], qv[cb][kk], acc[mb][cb], 0, 0, 0);
    }

    // in-register guarded top-5 update (acc IS d2'); overlaps staging latency
#pragma unroll
    for (int mb = 0; mb < 4; ++mb)
#pragma unroll
      for (int cb = 0; cb < 2; ++cb) {
        float c0 = acc[mb][cb][0], c1 = acc[mb][cb][1];
        float c2 = acc[mb][cb][2], c3 = acc[mb][cb][3];
        float m01 = fminf(fminf(c0, c1), fminf(c2, c3));
        if (m01 < t5[cb][4]) {
          ins5(c0, t5[cb][0], t5[cb][1], t5[cb][2], t5[cb][3], t5[cb][4]);
          ins5(c1, t5[cb][0], t5[cb][1], t5[cb][2], t5[cb][3], t5[cb][4]);
          ins5(c2, t5[cb][0], t5[cb][1], t5[cb][2], t5[cb][3], t5[cb][4]);
          ins5(c3, t5[cb][0], t5[cb][1], t5[cb][2], t5[cb][3], t5[cb][4]);
        }
      }
    __syncthreads();   // prefetch drained; Bs[cur] reads done -> next tile
  }

  // merge across the 4 lane-groups holding the same q-col (lanes j, j+16, j+32, j+48)
#pragma unroll
  for (int cb = 0; cb < 2; ++cb) {
    float r0 = __shfl_xor(t5[cb][0], 16), r1 = __shfl_xor(t5[cb][1], 16),
          r2 = __shfl_xor(t5[cb][2], 16), r3 = __shfl_xor(t5[cb][3], 16),
          r4 = __shfl_xor(t5[cb][4], 16);
    ins5(r0, t5[cb][0], t5[cb][1], t5[cb][2], t5[cb][3], t5[cb][4]);
    ins5(r1, t5[cb][0], t5[cb][1], t5[cb][2], t5[cb][3], t5[cb][4]);
    ins5(r2, t5[cb][0], t5[cb][1], t5[cb][2], t5[cb][3], t5[cb][4]);
    ins5(r3, t5[cb][0], t5[cb][1], t5[cb][2], t5[cb][3], t5[cb][4]);
    ins5(r4, t5[cb][0], t5[cb][1], t5[cb][2], t5[cb][3], t5[cb][4]);
    r0 = __shfl_xor(t5[cb][0], 32); r1 = __shfl_xor(t5[cb][1], 32);
    r2 = __shfl_xor(t5[cb][2], 32); r3 = __shfl_xor(t5[cb][3], 32);
    r4 = __shfl_xor(t5[cb][4], 32);
    ins5(r0, t5[cb][0], t5[cb][1], t5[cb][2], t5[cb][3], t5[cb][4]);
    ins5(r1, t5[cb][0], t5[cb][1], t5[cb][2], t5[cb][3], t5[cb][4]);
    ins5(r2, t5[cb][0], t5[cb][1], t5[cb][2], t5[cb][3], t5[cb][4]);
    ins5(r3, t5[cb][0], t5[cb][1], t5[cb][2], t5[cb][3], t5[cb][4]);
    ins5(r4, t5[cb][0], t5[cb][1], t5[cb][2], t5[cb][3], t5[cb][4]);
  }
  if (lane < 16) {
#pragma unroll
    for (int cb = 0; cb < 2; ++cb) {
      int grow = row0 + wave * 32 + cb * 16 + l15;
      float* o = kp + ((size_t)grow * NSPLIT + split) * 5;
      o[0] = t5[cb][0]; o[1] = t5[cb][1]; o[2] = t5[cb][2]; o[3] = t5[cb][3]; o[4] = t5[cb][4];
    }
  }
}

// ================= fused mid: q row-norms + Mahalanobis =================
template<int C>
DEV void rownorm_dev(const u16* __restrict__ x, float* __restrict__ out, int bid, int tid) {
  int row = bid * 4 + (tid >> 6);
  int lane = tid & 63;
  constexpr int E = C / 64;
  const u16* p = x + (size_t)row * C + lane * E;
  float s = 0.f;
#pragma unroll
  for (int i = 0; i < E; ++i) { float v = bf2f(p[i]); s += v * v; }
#pragma unroll
  for (int m = 1; m < 64; m <<= 1) s += __shfl_xor(s, m);
  if (lane == 0) out[row] = s;
}

template<int C>
DEV void maha_dev(const u16* __restrict__ qfb, const float* __restrict__ mu,
                  const u16* __restrict__ icovb, float* __restrict__ mh,
                  u16* As, float* muS, int bid, int tid) {
  constexpr int QT = 64, KCH = C / 8;
  int wave = tid >> 6, lane = tid & 63;
  int row0 = bid * QT;

  for (int i = tid; i < C; i += 256) muS[i] = mu[i];
  __syncthreads();
  for (int u = tid; u < QT * KCH; u += 256) {
    int r = u / KCH, cc = u % KCH;
    bf8v v = *(const bf8v*)(qfb + (size_t)(row0 + r) * C + cc * 8);
    s8v d;
#pragma unroll
    for (int i = 0; i < 8; ++i) d[i] = (short)f2bf((float)v[i] - muS[cc * 8 + i]);
    *(s8v*)(As + r * C + ((cc ^ (r & 7)) << 3)) = d;
  }
  __syncthreads();

  int arow = wave * 16 + (lane & 15);
  int kb = lane >> 4;
  float mm[4] = {0.f, 0.f, 0.f, 0.f};
#pragma unroll
  for (int cb = 0; cb < C / 16; ++cb) {
    f4v acc = (f4v){0.f, 0.f, 0.f, 0.f};
    int bcol = cb * 16 + (lane & 15);
#pragma unroll
    for (int kk = 0; kk < C / 32; ++kk) {
      int kc = kk * 4 + kb;
      bf8v a = *(const bf8v*)(As + arow * C + ((kc ^ (arow & 7)) << 3));
      bf8v b = *(const bf8v*)(icovb + (size_t)bcol * C + kc * 8);  // global, L2-hot
      acc = __builtin_amdgcn_mfma_f32_16x16x32_bf16(a, b, acc, 0, 0, 0);
    }
#pragma unroll
    for (int r = 0; r < 4; ++r) {
      int row = wave * 16 + (lane >> 4) * 4 + r;
      int col = cb * 16 + (lane & 15);
      float dv = bf2f(As[row * C + (((col >> 3) ^ (row & 7)) << 3) + (col & 7)]);
      mm[r] += acc[r] * dv;
    }
  }
#pragma unroll
  for (int r = 0; r < 4; ++r) {
    float v = mm[r];
    v += __shfl_xor(v, 1); v += __shfl_xor(v, 2);
    v += __shfl_xor(v, 4); v += __shfl_xor(v, 8);
    if ((lane & 15) == 0)
      mh[row0 + wave * 16 + (lane >> 4) * 4 + r] = sqrtf(fmaxf(v, EPSF));
  }
}

__global__ __launch_bounds__(256) void k_mid(
    const u16* __restrict__ qf2b, const u16* __restrict__ qf3b,
    const float* __restrict__ mean2, const float* __restrict__ mean3,
    const u16* __restrict__ ic2b, const u16* __restrict__ ic3b,
    float* __restrict__ qn2, float* __restrict__ qn3,
    float* __restrict__ mh2, float* __restrict__ mh3) {
  __shared__ alignas(16) u16 As[64 * 256];
  __shared__ float muS[256];
  int bid = blockIdx.x, tid = threadIdx.x;
  if (bid < 3136)       rownorm_dev<128>(qf2b, qn2, bid, tid);
  else if (bid < 6272)  rownorm_dev<256>(qf3b, qn3, bid - 3136, tid);
  else if (bid < 6468)  maha_dev<128>(qf2b, mean2, ic2b, mh2, As, muS, bid - 6272, tid);
  else                  maha_dev<256>(qf3b, mean3, ic3b, mh3, As, muS, bid - 6468, tid);
}

// ================= combine: merge knn splits (+qn), build maps =================
// kp layout [n][S][5] -> per-thread reads are contiguous
template<int S>
DEV float knn_merge(const float* kp, int n, float qv) {
  float t0 = 1e30f, t1 = 1e30f, t2 = 1e30f, t3 = 1e30f, t4 = 1e30f;
  const float* p = kp + (size_t)n * S * 5;
#pragma unroll
  for (int i = 0; i < S * 5; ++i) ins5(p[i], t0, t1, t2, t3, t4);
  return 0.2f * (sqrtf(fmaxf(t0 + qv, EPSF)) + sqrtf(fmaxf(t1 + qv, EPSF)) +
                 sqrtf(fmaxf(t2 + qv, EPSF)) + sqrtf(fmaxf(t3 + qv, EPSF)) +
                 sqrtf(fmaxf(t4 + qv, EPSF)));
}

__global__ __launch_bounds__(256) void k_combine(
    const float* __restrict__ kp2, const float* __restrict__ kp3,
    const float* __restrict__ qn2, const float* __restrict__ qn3,
    const float* __restrict__ mh2, const float* __restrict__ mh3,
    float* __restrict__ out) {
  int n = blockIdx.x * 256 + threadIdx.x;   // exact: 49*256 == NQ
  float m2v = 0.5f * (knn_merge<16>(kp2, n, qn2[n]) + mh2[n]);
  float m3v = 0.5f * (knn_merge<8>(kp3, n, qn3[n]) + mh3[n]);
  out[16 + n] = 0.5f * (m2v + m3v);
  out[16 + NQ + n] = m2v;
  out[16 + 2 * NQ + n] = m3v;
}

// ================= per-image top-10 mean over 784-pixel map =================
__global__ __launch_bounds__(256) void k_top10(const float* __restrict__ comb, float* __restrict__ pred) {
  __shared__ float vals[1024];
  __shared__ float rv[256];
  __shared__ int ri[256];
  __shared__ float ssum;
  int b = blockIdx.x, tid = threadIdx.x;
  for (int i = tid; i < 1024; i += 256) vals[i] = (i < PP) ? comb[b * PP + i] : -1e30f;
  if (tid == 0) ssum = 0.f;
  __syncthreads();
  for (int it = 0; it < 10; ++it) {
    float bv = -1e30f; int bi = 0;
    for (int i = tid; i < 1024; i += 256) { float v = vals[i]; if (v > bv) { bv = v; bi = i; } }
    rv[tid] = bv; ri[tid] = bi;
    __syncthreads();
    for (int s = 128; s; s >>= 1) {
      if (tid < s && rv[tid + s] > rv[tid]) { rv[tid] = rv[tid + s]; ri[tid] = ri[tid + s]; }
      __syncthreads();
    }
    if (tid == 0) { ssum += rv[0]; vals[ri[0]] = -1e30f; }
    __syncthreads();
  }
  if (tid == 0) pred[b] = ssum * 0.1f;
}

extern "C" void kernel_launch(void* const* d_in, const int* in_sizes, int n_in,
                              void* d_out, int out_size, void* d_ws, size_t ws_size,
                              hipStream_t stream) {
  const float* q2    = (const float*)d_in[0];
  const float* q3    = (const float*)d_in[1];
  const float* mem2  = (const float*)d_in[2];
  const float* mem3  = (const float*)d_in[3];
  const float* mean2 = (const float*)d_in[4];
  const float* mean3 = (const float*)d_in[5];
  const float* icov2 = (const float*)d_in[6];
  const float* icov3 = (const float*)d_in[7];
  float* out = (float*)d_out;

  char* w = (char*)d_ws;
  auto alloc = [&](size_t bytes) { void* p = (void*)w; w += (bytes + 255) & ~(size_t)255; return p; };
  u16* qf2b = (u16*)alloc((size_t)NQ * 128 * 2);
  u16* qf3b = (u16*)alloc((size_t)NQ * 256 * 2);
  u16* m2b  = (u16*)alloc((size_t)MM * 128 * 2);
  u16* m3b  = (u16*)alloc((size_t)MM * 256 * 2);
  u16* ic2b = (u16*)alloc((size_t)128 * 128 * 2);
  u16* ic3b = (u16*)alloc((size_t)256 * 256 * 2);
  float* qn2 = (float*)alloc((size_t)NQ * 4);
  float* qn3 = (float*)alloc((size_t)NQ * 4);
  float* mn2 = (float*)alloc((size_t)MM * 4);
  float* mn3 = (float*)alloc((size_t)MM * 4);
  float* kp2 = (float*)alloc((size_t)NQ * 16 * 5 * 4);
  float* kp3 = (float*)alloc((size_t)NQ * 8 * 5 * 4);
  float* mh2 = (float*)alloc((size_t)NQ * 4);
  float* mh3 = (float*)alloc((size_t)NQ * 4);

  // fused prep: pack_mem2(2048) | pack_mem3(2048) | icov2(8) | icov3(32) | pack_q2(784) | pack_q3(1568)
  k_prep<<<6488, 256, 0, stream>>>(q2, q3, mem2, mem3, icov2, icov3,
                                   qf2b, qf3b, m2b, m3b, ic2b, ic3b, mn2, mn3);

  // C=256: dbuf LDS 65KB -> 2 blocks/CU; C=128: 33KB -> 3 blocks/CU (VGPR-capped)
  k_score<256, 8, 2><<<(NQ / 128) * 8, 256, 0, stream>>>(qf3b, m3b, mn3, kp3);
  k_score<128, 16, 3><<<(NQ / 128) * 16, 256, 0, stream>>>(qf2b, m2b, mn2, kp2);

  // fused mid: rownorm_q2(3136) | rownorm_q3(3136) | maha128(196) | maha256(196)
  k_mid<<<6664, 256, 0, stream>>>(qf2b, qf3b, mean2, mean3, ic2b, ic3b, qn2, qn3, mh2, mh3);

  k_combine<<<NQ / 256, 256, 0, stream>>>(kp2, kp3, qn2, qn3, mh2, mh3, out);
  k_top10<<<16, 256, 0, stream>>>(out + 16, out);

  (void)in_sizes; (void)n_in; (void)out_size; (void)ws_size;
}

// Round 8
// 242.646 us; speedup vs baseline: 1.0539x; 1.0539x over previous
//
#include <hip/hip_runtime.h>

typedef unsigned short u16;
typedef unsigned int u32;
typedef __attribute__((ext_vector_type(8))) __bf16 bf8v;   // MFMA A/B operand (8 bf16)
typedef __attribute__((ext_vector_type(8))) short s8v;     // same bits, for packing
typedef __attribute__((ext_vector_type(4))) float f4v;     // MFMA C/D (16x16)

#define DEV static __device__ __forceinline__

constexpr int NQ = 12544;   // B*H*W = 16*28*28
constexpr int MM = 8192;    // memory bank rows
constexpr int PP = 784;     // H*W
constexpr float EPSF = 1e-12f;

DEV u16 f2bf(float f) {  // RNE f32 -> bf16 (inputs are finite normals)
  u32 u = __float_as_uint(f);
  return (u16)((u + 0x7FFFu + ((u >> 16) & 1u)) >> 16);
}
DEV float bf2f(u16 h) { return __uint_as_float((u32)h << 16); }

// async 16B global -> LDS (wave-uniform LDS base + lane*16B; per-lane global src)
DEV void gl2lds16(const u16* g, u16* l) {
  __builtin_amdgcn_global_load_lds(
      (const __attribute__((address_space(1))) unsigned int*)(g),
      (__attribute__((address_space(3))) unsigned int*)(l), 16, 0, 0);
}

// branchless sorted insert: keep 5 smallest in a0<=..<=a4
DEV void ins5(float v, float& a0, float& a1, float& a2, float& a3, float& a4) {
  float hi;
  hi = fmaxf(v, a0); a0 = fminf(v, a0); v = hi;
  hi = fmaxf(v, a1); a1 = fminf(v, a1); v = hi;
  hi = fmaxf(v, a2); a2 = fminf(v, a2); v = hi;
  hi = fmaxf(v, a3); a3 = fminf(v, a3); v = hi;
  a4 = fminf(v, a4);
}

// ================= fused prep =================
DEV void pack_bf16_dev(const float* __restrict__ x, u16* __restrict__ y, int bid, int tid) {
  int g = bid * 256 + tid;
  const float4* px = (const float4*)x + (size_t)g * 2;
  float4 a = px[0], b = px[1];
  s8v o;
  o[0] = (short)f2bf(a.x); o[1] = (short)f2bf(a.y); o[2] = (short)f2bf(a.z); o[3] = (short)f2bf(a.w);
  o[4] = (short)f2bf(b.x); o[5] = (short)f2bf(b.y); o[6] = (short)f2bf(b.z); o[7] = (short)f2bf(b.w);
  ((s8v*)y)[g] = o;
}

// mem pack: store -2*m (exact bf16 scale) K-MAJOR in global: yT[chunk][row][8],
// so score staging of a chunk-column is 64 lanes x contiguous 16B (coalesced).
// norm from ORIGINAL f32 values.
template<int C>
DEV void pack_mem_dev(const float* __restrict__ x, u16* __restrict__ yT, float* __restrict__ nrm,
                      int bid, int tid) {
  int row = bid * 4 + (tid >> 6), lane = tid & 63;
  constexpr int E = C / 64;
  const float* src = x + (size_t)row * C + lane * E;
  float s = 0.f;
  if constexpr (E == 4) {
    float4 v = *(const float4*)src;
    s = v.x * v.x + v.y * v.y + v.z * v.z + v.w * v.w;
    u32 lo = (u32)f2bf(-2.f * v.x) | ((u32)f2bf(-2.f * v.y) << 16);
    u32 hi = (u32)f2bf(-2.f * v.z) | ((u32)f2bf(-2.f * v.w) << 16);
    size_t di = ((size_t)(lane >> 1) * MM + row) * 8 + (lane & 1) * 4;
    *(uint2*)(yT + di) = make_uint2(lo, hi);
  } else {
    float2 v = *(const float2*)src;
    s = v.x * v.x + v.y * v.y;
    size_t di = ((size_t)(lane >> 2) * MM + row) * 8 + (lane & 3) * 2;
    *(u32*)(yT + di) = (u32)f2bf(-2.f * v.x) | ((u32)f2bf(-2.f * v.y) << 16);
  }
#pragma unroll
  for (int m = 1; m < 64; m <<= 1) s += __shfl_xor(s, m);
  if (lane == 0) nrm[row] = s;
}

template<int C>
DEV void pack_q_dev(const float* __restrict__ q, u16* __restrict__ qfb, int bid, int tid) {
  int g = bid * 256 + tid;   // [0, NQ * C/8); NQ%256==0 so cc is block-uniform
  int n = g % NQ;
  int cc = g / NQ;
  int b = n / PP, p = n % PP;
  int c0 = cc * 8;
  const float* src = q + ((size_t)b * C + c0) * PP + p;   // lanes: consecutive p -> coalesced
  s8v o;
#pragma unroll
  for (int i = 0; i < 8; ++i) o[i] = (short)f2bf(src[(size_t)i * PP]);
  ((s8v*)qfb)[((size_t)n * C + c0) >> 3] = o;
}

__global__ __launch_bounds__(256) void k_prep(
    const float* __restrict__ q2, const float* __restrict__ q3,
    const float* __restrict__ mem2, const float* __restrict__ mem3,
    const float* __restrict__ icov2, const float* __restrict__ icov3,
    u16* __restrict__ qf2b, u16* __restrict__ qf3b,
    u16* __restrict__ m2t, u16* __restrict__ m3t,
    u16* __restrict__ ic2b, u16* __restrict__ ic3b,
    float* __restrict__ mn2, float* __restrict__ mn3) {
  int bid = blockIdx.x, tid = threadIdx.x;
  if (bid < 2048)       pack_mem_dev<128>(mem2, m2t, mn2, bid, tid);
  else if (bid < 4096)  pack_mem_dev<256>(mem3, m3t, mn3, bid - 2048, tid);
  else if (bid < 4104)  pack_bf16_dev(icov2, ic2b, bid - 4096, tid);
  else if (bid < 4136)  pack_bf16_dev(icov3, ic3b, bid - 4104, tid);
  else if (bid < 4920)  pack_q_dev<128>(q2, qf2b, bid - 4136, tid);
  else                  pack_q_dev<256>(q3, qf3b, bid - 4920, tid);
}

// ================= fused distances + per-row 5 smallest d2' =================
// D = mfma(-2m_frag, q_frag), C-init = |m|^2 -> acc IS d2'. 8 waves (512 thr).
// memT is K-major in global -> staging coalesced (1KB/chunk-col instr);
// LDS [chunk][row] -> ds_read_b128 all-immediate offsets, conflict-free (R7, 0 confl).
// CB q-16-blocks per wave; per-q-row top-5 in registers. Double-buffered, 1 barrier/tile.
template<int C, int CB, int NSPLIT>
__global__ __launch_bounds__(512, 4)
void k_score(const u16* __restrict__ qf, const u16* __restrict__ memT,
             const float* __restrict__ mn, float* __restrict__ kp) {
  constexpr int MT = 64, MS = MM / NSPLIT, NT = MS / MT;
  constexpr int CPR = C / 8;              // 16B chunks per mem row
  constexpr int SIT = CPR / 8;            // staging iters per wave per tile
  constexpr int QROWS = 8 * 16 * CB;      // q rows per block
  constexpr int RT = NQ / QROWS;
  __shared__ alignas(16) u16 Bs[2][CPR * 64 * 8];   // [chunk][row][8]
  __shared__ alignas(16) float mnS[2][MT];

  const int tid = threadIdx.x, wave = tid >> 6, lane = tid & 63;
  const int l15 = lane & 15, kb = lane >> 4, g4 = (lane >> 4) << 2;
  const int rt = blockIdx.x % RT, split = blockIdx.x / RT;   // split-major: mem slice L2-hot per XCD
  const int row0 = rt * QROWS, mb0 = split * MS;

  // q fragments (B operand; loop-invariant) -> registers, pinned.
  bf8v qv[CB][C / 32];
#pragma unroll
  for (int cb = 0; cb < CB; ++cb)
#pragma unroll
    for (int kk = 0; kk < C / 32; ++kk)
      qv[cb][kk] = *(const bf8v*)(qf + (size_t)(row0 + (wave * CB + cb) * 16 + l15) * C + ((kk * 4 + kb) << 3));
#pragma unroll
  for (int cb = 0; cb < CB; ++cb)
#pragma unroll
    for (int kk = 0; kk < C / 32; ++kk)
      asm volatile("" : "+v"(qv[cb][kk]));

  auto STAGE = [&](int buf, int t) {
    const int mrow0 = mb0 + t * MT;
#pragma unroll
    for (int it = 0; it < SIT; ++it) {
      int cp = wave + it * 8;
      gl2lds16(memT + ((size_t)cp * MM + mrow0 + lane) * 8, Bs[buf] + (cp * 64 + lane) * 8);
    }
    if (tid < 16) gl2lds16((const u16*)(mn + mrow0) + tid * 8, (u16*)mnS[buf] + tid * 8);
  };

  STAGE(0, 0);
  __syncthreads();   // vmcnt drained -> buf0 ready

  float t5[CB][5];
#pragma unroll
  for (int cb = 0; cb < CB; ++cb)
#pragma unroll
    for (int i = 0; i < 5; ++i) t5[cb][i] = 1e30f;

  for (int mt = 0; mt < NT; ++mt) {
    const int cur = mt & 1;
    if (mt + 1 < NT) STAGE(cur ^ 1, mt + 1);   // async prefetch into other buffer

    f4v mnv[4];
#pragma unroll
    for (int mb = 0; mb < 4; ++mb) mnv[mb] = *(const f4v*)(mnS[cur] + mb * 16 + g4);

    f4v acc[4][CB];   // init = |m|^2
#pragma unroll
    for (int mb = 0; mb < 4; ++mb)
#pragma unroll
      for (int cb = 0; cb < CB; ++cb) acc[mb][cb] = mnv[mb];

    const u16* Bb = Bs[cur] + kb * 512 + l15 * 8;   // per-lane base; rest immediates
#pragma unroll
    for (int kk = 0; kk < C / 32; ++kk) {
      bf8v mf[4];
#pragma unroll
      for (int mb = 0; mb < 4; ++mb)
        mf[mb] = *(const bf8v*)(Bb + kk * 2048 + mb * 128);
#pragma unroll
      for (int mb = 0; mb < 4; ++mb)
#pragma unroll
        for (int cb = 0; cb < CB; ++cb)
          acc[mb][cb] = __builtin_amdgcn_mfma_f32_16x16x32_bf16(mf[mb], qv[cb][kk], acc[mb][cb], 0, 0, 0);
    }

    // in-register guarded top-5 update (overlaps prefetch latency)
#pragma unroll
    for (int mb = 0; mb < 4; ++mb)
#pragma unroll
      for (int cb = 0; cb < CB; ++cb) {
        float c0 = acc[mb][cb][0], c1 = acc[mb][cb][1];
        float c2 = acc[mb][cb][2], c3 = acc[mb][cb][3];
        float m01 = fminf(fminf(c0, c1), fminf(c2, c3));
        if (m01 < t5[cb][4]) {
          ins5(c0, t5[cb][0], t5[cb][1], t5[cb][2], t5[cb][3], t5[cb][4]);
          ins5(c1, t5[cb][0], t5[cb][1], t5[cb][2], t5[cb][3], t5[cb][4]);
          ins5(c2, t5[cb][0], t5[cb][1], t5[cb][2], t5[cb][3], t5[cb][4]);
          ins5(c3, t5[cb][0], t5[cb][1], t5[cb][2], t5[cb][3], t5[cb][4]);
        }
      }
    __syncthreads();   // prefetch drained; Bs[cur] reads done -> next tile
  }

  // merge the 4 lane-groups holding the same q-col (lanes j, j+16, j+32, j+48)
#pragma unroll
  for (int cb = 0; cb < CB; ++cb) {
#pragma unroll
    for (int st = 16; st <= 32; st <<= 1) {
      float r0 = __shfl_xor(t5[cb][0], st), r1 = __shfl_xor(t5[cb][1], st),
            r2 = __shfl_xor(t5[cb][2], st), r3 = __shfl_xor(t5[cb][3], st),
            r4 = __shfl_xor(t5[cb][4], st);
      ins5(r0, t5[cb][0], t5[cb][1], t5[cb][2], t5[cb][3], t5[cb][4]);
      ins5(r1, t5[cb][0], t5[cb][1], t5[cb][2], t5[cb][3], t5[cb][4]);
      ins5(r2, t5[cb][0], t5[cb][1], t5[cb][2], t5[cb][3], t5[cb][4]);
      ins5(r3, t5[cb][0], t5[cb][1], t5[cb][2], t5[cb][3], t5[cb][4]);
      ins5(r4, t5[cb][0], t5[cb][1], t5[cb][2], t5[cb][3], t5[cb][4]);
    }
  }
  if (lane < 16) {
#pragma unroll
    for (int cb = 0; cb < CB; ++cb) {
      int grow = row0 + (wave * CB + cb) * 16 + l15;
      float* o = kp + ((size_t)grow * NSPLIT + split) * 5;
      o[0] = t5[cb][0]; o[1] = t5[cb][1]; o[2] = t5[cb][2]; o[3] = t5[cb][3]; o[4] = t5[cb][4];
    }
  }
}

// ================= fused mid: q row-norms + Mahalanobis =================
template<int C>
DEV void rownorm_dev(const u16* __restrict__ x, float* __restrict__ out, int bid, int tid) {
  int row = bid * 4 + (tid >> 6);
  int lane = tid & 63;
  constexpr int E = C / 64;
  const u16* p = x + (size_t)row * C + lane * E;
  float s = 0.f;
#pragma unroll
  for (int i = 0; i < E; ++i) { float v = bf2f(p[i]); s += v * v; }
#pragma unroll
  for (int m = 1; m < 64; m <<= 1) s += __shfl_xor(s, m);
  if (lane == 0) out[row] = s;
}

template<int C>
DEV void maha_dev(const u16* __restrict__ qfb, const float* __restrict__ mu,
                  const u16* __restrict__ icovb, float* __restrict__ mh,
                  u16* As, float* muS, int bid, int tid) {
  constexpr int QT = 64, KCH = C / 8;
  int wave = tid >> 6, lane = tid & 63;
  int row0 = bid * QT;

  for (int i = tid; i < C; i += 256) muS[i] = mu[i];
  __syncthreads();
  for (int u = tid; u < QT * KCH; u += 256) {
    int r = u / KCH, cc = u % KCH;
    bf8v v = *(const bf8v*)(qfb + (size_t)(row0 + r) * C + cc * 8);
    s8v d;
#pragma unroll
    for (int i = 0; i < 8; ++i) d[i] = (short)f2bf((float)v[i] - muS[cc * 8 + i]);
    *(s8v*)(As + r * C + ((cc ^ (r & 7)) << 3)) = d;
  }
  __syncthreads();

  int arow = wave * 16 + (lane & 15);
  int kb = lane >> 4;
  float mm[4] = {0.f, 0.f, 0.f, 0.f};
#pragma unroll
  for (int cb = 0; cb < C / 16; ++cb) {
    f4v acc = (f4v){0.f, 0.f, 0.f, 0.f};
    int bcol = cb * 16 + (lane & 15);
#pragma unroll
    for (int kk = 0; kk < C / 32; ++kk) {
      int kc = kk * 4 + kb;
      bf8v a = *(const bf8v*)(As + arow * C + ((kc ^ (arow & 7)) << 3));
      bf8v b = *(const bf8v*)(icovb + (size_t)bcol * C + kc * 8);  // global, L2-hot
      acc = __builtin_amdgcn_mfma_f32_16x16x32_bf16(a, b, acc, 0, 0, 0);
    }
#pragma unroll
    for (int r = 0; r < 4; ++r) {
      int row = wave * 16 + (lane >> 4) * 4 + r;
      int col = cb * 16 + (lane & 15);
      float dv = bf2f(As[row * C + (((col >> 3) ^ (row & 7)) << 3) + (col & 7)]);
      mm[r] += acc[r] * dv;
    }
  }
#pragma unroll
  for (int r = 0; r < 4; ++r) {
    float v = mm[r];
    v += __shfl_xor(v, 1); v += __shfl_xor(v, 2);
    v += __shfl_xor(v, 4); v += __shfl_xor(v, 8);
    if ((lane & 15) == 0)
      mh[row0 + wave * 16 + (lane >> 4) * 4 + r] = sqrtf(fmaxf(v, EPSF));
  }
}

__global__ __launch_bounds__(256) void k_mid(
    const u16* __restrict__ qf2b, const u16* __restrict__ qf3b,
    const float* __restrict__ mean2, const float* __restrict__ mean3,
    const u16* __restrict__ ic2b, const u16* __restrict__ ic3b,
    float* __restrict__ qn2, float* __restrict__ qn3,
    float* __restrict__ mh2, float* __restrict__ mh3) {
  __shared__ alignas(16) u16 As[64 * 256];
  __shared__ float muS[256];
  int bid = blockIdx.x, tid = threadIdx.x;
  if (bid < 3136)       rownorm_dev<128>(qf2b, qn2, bid, tid);
  else if (bid < 6272)  rownorm_dev<256>(qf3b, qn3, bid - 3136, tid);
  else if (bid < 6468)  maha_dev<128>(qf2b, mean2, ic2b, mh2, As, muS, bid - 6272, tid);
  else                  maha_dev<256>(qf3b, mean3, ic3b, mh3, As, muS, bid - 6468, tid);
}

// ================= combine: merge knn splits (+qn), build maps =================
template<int S>
DEV float knn_merge(const float* kp, int n, float qv) {
  float t0 = 1e30f, t1 = 1e30f, t2 = 1e30f, t3 = 1e30f, t4 = 1e30f;
  const float* p = kp + (size_t)n * S * 5;
#pragma unroll
  for (int i = 0; i < S * 5; ++i) ins5(p[i], t0, t1, t2, t3, t4);
  return 0.2f * (sqrtf(fmaxf(t0 + qv, EPSF)) + sqrtf(fmaxf(t1 + qv, EPSF)) +
                 sqrtf(fmaxf(t2 + qv, EPSF)) + sqrtf(fmaxf(t3 + qv, EPSF)) +
                 sqrtf(fmaxf(t4 + qv, EPSF)));
}

__global__ __launch_bounds__(256) void k_combine(
    const float* __restrict__ kp2, const float* __restrict__ kp3,
    const float* __restrict__ qn2, const float* __restrict__ qn3,
    const float* __restrict__ mh2, const float* __restrict__ mh3,
    float* __restrict__ out) {
  int n = blockIdx.x * 256 + threadIdx.x;   // exact: 49*256 == NQ
  float m2v = 0.5f * (knn_merge<16>(kp2, n, qn2[n]) + mh2[n]);
  float m3v = 0.5f * (knn_merge<8>(kp3, n, qn3[n]) + mh3[n]);
  out[16 + n] = 0.5f * (m2v + m3v);
  out[16 + NQ + n] = m2v;
  out[16 + 2 * NQ + n] = m3v;
}

// ================= per-image top-10 mean over 784-pixel map =================
__global__ __launch_bounds__(256) void k_top10(const float* __restrict__ comb, float* __restrict__ pred) {
  __shared__ float vals[1024];
  __shared__ float rv[256];
  __shared__ int ri[256];
  __shared__ float ssum;
  int b = blockIdx.x, tid = threadIdx.x;
  for (int i = tid; i < 1024; i += 256) vals[i] = (i < PP) ? comb[b * PP + i] : -1e30f;
  if (tid == 0) ssum = 0.f;
  __syncthreads();
  for (int it = 0; it < 10; ++it) {
    float bv = -1e30f; int bi = 0;
    for (int i = tid; i < 1024; i += 256) { float v = vals[i]; if (v > bv) { bv = v; bi = i; } }
    rv[tid] = bv; ri[tid] = bi;
    __syncthreads();
    for (int s = 128; s; s >>= 1) {
      if (tid < s && rv[tid + s] > rv[tid]) { rv[tid] = rv[tid + s]; ri[tid] = ri[tid + s]; }
      __syncthreads();
    }
    if (tid == 0) { ssum += rv[0]; vals[ri[0]] = -1e30f; }
    __syncthreads();
  }
  if (tid == 0) pred[b] = ssum * 0.1f;
}

extern "C" void kernel_launch(void* const* d_in, const int* in_sizes, int n_in,
                              void* d_out, int out_size, void* d_ws, size_t ws_size,
                              hipStream_t stream) {
  const float* q2    = (const float*)d_in[0];
  const float* q3    = (const float*)d_in[1];
  const float* mem2  = (const float*)d_in[2];
  const float* mem3  = (const float*)d_in[3];
  const float* mean2 = (const float*)d_in[4];
  const float* mean3 = (const float*)d_in[5];
  const float* icov2 = (const float*)d_in[6];
  const float* icov3 = (const float*)d_in[7];
  float* out = (float*)d_out;

  char* w = (char*)d_ws;
  auto alloc = [&](size_t bytes) { void* p = (void*)w; w += (bytes + 255) & ~(size_t)255; return p; };
  u16* qf2b = (u16*)alloc((size_t)NQ * 128 * 2);
  u16* qf3b = (u16*)alloc((size_t)NQ * 256 * 2);
  u16* m2t  = (u16*)alloc((size_t)MM * 128 * 2);
  u16* m3t  = (u16*)alloc((size_t)MM * 256 * 2);
  u16* ic2b = (u16*)alloc((size_t)128 * 128 * 2);
  u16* ic3b = (u16*)alloc((size_t)256 * 256 * 2);
  float* qn2 = (float*)alloc((size_t)NQ * 4);
  float* qn3 = (float*)alloc((size_t)NQ * 4);
  float* mn2 = (float*)alloc((size_t)MM * 4);
  float* mn3 = (float*)alloc((size_t)MM * 4);
  float* kp2 = (float*)alloc((size_t)NQ * 16 * 5 * 4);
  float* kp3 = (float*)alloc((size_t)NQ * 8 * 5 * 4);
  float* mh2 = (float*)alloc((size_t)NQ * 4);
  float* mh3 = (float*)alloc((size_t)NQ * 4);

  // fused prep: pack_mem2(2048) | pack_mem3(2048) | icov2(8) | icov3(32) | pack_q2(784) | pack_q3(1568)
  k_prep<<<6488, 256, 0, stream>>>(q2, q3, mem2, mem3, icov2, icov3,
                                   qf2b, qf3b, m2t, m3t, ic2b, ic3b, mn2, mn3);

  // 8-wave blocks, 784 each; C=256: CB=1 (VGPR~95), C=128: CB=2 (VGPR~115)
  k_score<256, 1, 8><<<784, 512, 0, stream>>>(qf3b, m3t, mn3, kp3);
  k_score<128, 2, 16><<<784, 512, 0, stream>>>(qf2b, m2t, mn2, kp2);

  // fused mid: rownorm_q2(3136) | rownorm_q3(3136) | maha128(196) | maha256(196)
  k_mid<<<6664, 256, 0, stream>>>(qf2b, qf3b, mean2, mean3, ic2b, ic3b, qn2, qn3, mh2, mh3);

  k_combine<<<NQ / 256, 256, 0, stream>>>(kp2, kp3, qn2, qn3, mh2, mh3, out);
  k_top10<<<16, 256, 0, stream>>>(out + 16, out);

  (void)in_sizes; (void)n_in; (void)out_size; (void)ws_size;
}

// Round 9
// 237.153 us; speedup vs baseline: 1.0783x; 1.0232x over previous
//
#include <hip/hip_runtime.h>

typedef unsigned short u16;
typedef unsigned int u32;
typedef __attribute__((ext_vector_type(8))) __bf16 bf8v;    // MFMA A/B operand (8 bf16)
typedef __attribute__((ext_vector_type(8))) short s8v;      // same bits, for packing
typedef __attribute__((ext_vector_type(4))) float f4v;
typedef __attribute__((ext_vector_type(16))) float f16v;    // 32x32 MFMA C/D

#define DEV static __device__ __forceinline__

constexpr int NQ = 12544;   // B*H*W = 16*28*28
constexpr int MM = 8192;    // memory bank rows
constexpr int PP = 784;     // H*W
constexpr float EPSF = 1e-12f;

DEV u16 f2bf(float f) {  // RNE f32 -> bf16 (inputs are finite normals)
  u32 u = __float_as_uint(f);
  return (u16)((u + 0x7FFFu + ((u >> 16) & 1u)) >> 16);
}
DEV float bf2f(u16 h) { return __uint_as_float((u32)h << 16); }

// async 16B global -> LDS (wave-uniform LDS base + lane*16B; per-lane global src)
DEV void gl2lds16(const u16* g, u16* l) {
  __builtin_amdgcn_global_load_lds(
      (const __attribute__((address_space(1))) unsigned int*)(g),
      (__attribute__((address_space(3))) unsigned int*)(l), 16, 0, 0);
}

// branchless sorted insert: keep 5 smallest in a0<=..<=a4
DEV void ins5(float v, float& a0, float& a1, float& a2, float& a3, float& a4) {
  float hi;
  hi = fmaxf(v, a0); a0 = fminf(v, a0); v = hi;
  hi = fmaxf(v, a1); a1 = fminf(v, a1); v = hi;
  hi = fmaxf(v, a2); a2 = fminf(v, a2); v = hi;
  hi = fmaxf(v, a3); a3 = fminf(v, a3); v = hi;
  a4 = fminf(v, a4);
}

// ================= fused prep =================
DEV void pack_bf16_dev(const float* __restrict__ x, u16* __restrict__ y, int bid, int tid) {
  int g = bid * 256 + tid;
  const float4* px = (const float4*)x + (size_t)g * 2;
  float4 a = px[0], b = px[1];
  s8v o;
  o[0] = (short)f2bf(a.x); o[1] = (short)f2bf(a.y); o[2] = (short)f2bf(a.z); o[3] = (short)f2bf(a.w);
  o[4] = (short)f2bf(b.x); o[5] = (short)f2bf(b.y); o[6] = (short)f2bf(b.z); o[7] = (short)f2bf(b.w);
  ((s8v*)y)[g] = o;
}

// mem pack: store -2*m (exact bf16 scale) K-MAJOR in global: yT[chunk][row][8];
// score staging of a chunk-column is then contiguous/coalesced. norm from f32.
template<int C>
DEV void pack_mem_dev(const float* __restrict__ x, u16* __restrict__ yT, float* __restrict__ nrm,
                      int bid, int tid) {
  int row = bid * 4 + (tid >> 6), lane = tid & 63;
  constexpr int E = C / 64;
  const float* src = x + (size_t)row * C + lane * E;
  float s = 0.f;
  if constexpr (E == 4) {
    float4 v = *(const float4*)src;
    s = v.x * v.x + v.y * v.y + v.z * v.z + v.w * v.w;
    u32 lo = (u32)f2bf(-2.f * v.x) | ((u32)f2bf(-2.f * v.y) << 16);
    u32 hi = (u32)f2bf(-2.f * v.z) | ((u32)f2bf(-2.f * v.w) << 16);
    size_t di = ((size_t)(lane >> 1) * MM + row) * 8 + (lane & 1) * 4;
    *(uint2*)(yT + di) = make_uint2(lo, hi);
  } else {
    float2 v = *(const float2*)src;
    s = v.x * v.x + v.y * v.y;
    size_t di = ((size_t)(lane >> 2) * MM + row) * 8 + (lane & 3) * 2;
    *(u32*)(yT + di) = (u32)f2bf(-2.f * v.x) | ((u32)f2bf(-2.f * v.y) << 16);
  }
#pragma unroll
  for (int m = 1; m < 64; m <<= 1) s += __shfl_xor(s, m);
  if (lane == 0) nrm[row] = s;
}

template<int C>
DEV void pack_q_dev(const float* __restrict__ q, u16* __restrict__ qfb, int bid, int tid) {
  int g = bid * 256 + tid;   // [0, NQ * C/8); NQ%256==0 so cc is block-uniform
  int n = g % NQ;
  int cc = g / NQ;
  int b = n / PP, p = n % PP;
  int c0 = cc * 8;
  const float* src = q + ((size_t)b * C + c0) * PP + p;   // lanes: consecutive p -> coalesced
  s8v o;
#pragma unroll
  for (int i = 0; i < 8; ++i) o[i] = (short)f2bf(src[(size_t)i * PP]);
  ((s8v*)qfb)[((size_t)n * C + c0) >> 3] = o;
}

__global__ __launch_bounds__(256) void k_prep(
    const float* __restrict__ q2, const float* __restrict__ q3,
    const float* __restrict__ mem2, const float* __restrict__ mem3,
    const float* __restrict__ icov2, const float* __restrict__ icov3,
    u16* __restrict__ qf2b, u16* __restrict__ qf3b,
    u16* __restrict__ m2t, u16* __restrict__ m3t,
    u16* __restrict__ ic2b, u16* __restrict__ ic3b,
    float* __restrict__ mn2, float* __restrict__ mn3) {
  int bid = blockIdx.x, tid = threadIdx.x;
  if (bid < 2048)       pack_mem_dev<128>(mem2, m2t, mn2, bid, tid);
  else if (bid < 4096)  pack_mem_dev<256>(mem3, m3t, mn3, bid - 2048, tid);
  else if (bid < 4104)  pack_bf16_dev(icov2, ic2b, bid - 4096, tid);
  else if (bid < 4136)  pack_bf16_dev(icov3, ic3b, bid - 4104, tid);
  else if (bid < 4920)  pack_q_dev<128>(q2, qf2b, bid - 4136, tid);
  else                  pack_q_dev<256>(q3, qf3b, bid - 4920, tid);
}

// ================= fused distances + per-row 5 smallest d2' =================
// 32x32x16 MFMA: D = mfma(-2m_frag, q_frag), C-init = |m|^2 -> acc IS d2'.
// Wave = 32 mem x 32 q (2x FLOP per LDS byte vs 16x16 -- R8 lesson: LDS BW was
// the structural ceiling). Lane holds 16 candidates for ONE q-col (col=lane&31,
// row=(reg&3)+8*(reg>>2)+4*(lane>>5)); top-5 in regs; 1 shfl_xor(32) merge.
// MT=32 rows/tile; LDS [chunk][row] -> all-immediate conflict-free ds_read_b128.
// 8-wave blocks, double-buffered, 1 barrier/tile.
template<int C, int NSPLIT, int WPEU>
__global__ __launch_bounds__(512, WPEU)
void k_score(const u16* __restrict__ qf, const u16* __restrict__ memT,
             const float* __restrict__ mn, float* __restrict__ kp) {
  constexpr int MT = 32, MS = MM / NSPLIT, NT = MS / MT;
  constexpr int CHUNKS = C / 8;           // 16B chunks per mem row
  constexpr int SIT = CHUNKS / 16;        // staging instrs per wave per tile (2 chunks each)
  constexpr int QROWS = 8 * 32;           // q rows per block
  constexpr int RT = NQ / QROWS;          // 49
  __shared__ alignas(16) u16 Bs[2][CHUNKS * MT * 8];   // [chunk][row][8]
  __shared__ alignas(16) float mnS[2][MT];

  const int tid = threadIdx.x, wave = tid >> 6, lane = tid & 63;
  const int l31 = lane & 31, kh = lane >> 5;           // col / k-half
  const int rt = blockIdx.x % RT, split = blockIdx.x / RT;  // split-major: mem slice L2-hot
  const int row0 = rt * QROWS, mb0 = split * MS;

  // q fragments (B operand; loop-invariant) -> registers, pinned.
  // B layout: col = lane&31 (q row), k = kk*16 + (lane>>5)*8 + [0..8)
  bf8v qv[C / 16];
#pragma unroll
  for (int kk = 0; kk < C / 16; ++kk)
    qv[kk] = *(const bf8v*)(qf + (size_t)(row0 + wave * 32 + l31) * C + kk * 16 + kh * 8);
#pragma unroll
  for (int kk = 0; kk < C / 16; ++kk)
    asm volatile("" : "+v"(qv[kk]));

  auto STAGE = [&](int buf, int t) {
    const int mrow0 = mb0 + t * MT;
#pragma unroll
    for (int it = 0; it < SIT; ++it) {
      int cp2 = wave + it * 8;   // covers chunks 2*cp2, 2*cp2+1
      gl2lds16(memT + ((size_t)(cp2 * 2 + kh) * MM + mrow0 + l31) * 8,
               Bs[buf] + cp2 * 512 + lane * 8);
    }
    if (tid < 8) gl2lds16((const u16*)(mn + mrow0) + tid * 8, (u16*)mnS[buf] + tid * 8);
  };

  STAGE(0, 0);
  __syncthreads();   // vmcnt drained -> buf0 ready

  float t0 = 1e30f, t1 = 1e30f, t2 = 1e30f, t3 = 1e30f, t4 = 1e30f;

  for (int mt = 0; mt < NT; ++mt) {
    const int cur = mt & 1;
    if (mt + 1 < NT) STAGE(cur ^ 1, mt + 1);   // async prefetch into other buffer

    // C-init: acc reg r <-> mem row (r&3) + 8*(r>>2) + 4*kh
    f16v acc;
#pragma unroll
    for (int g = 0; g < 4; ++g) {
      f4v m4 = *(const f4v*)(mnS[cur] + g * 8 + kh * 4);
      acc[4 * g + 0] = m4[0]; acc[4 * g + 1] = m4[1];
      acc[4 * g + 2] = m4[2]; acc[4 * g + 3] = m4[3];
    }

    // A layout: row = lane&31, k = kk*16 + kh*8 + [0..8)
    const u16* Bb = Bs[cur] + l31 * 8 + kh * 256;   // u16 units; +kk*512
#pragma unroll
    for (int kk = 0; kk < C / 16; ++kk) {
      bf8v mf = *(const bf8v*)(Bb + kk * 512);
      acc = __builtin_amdgcn_mfma_f32_32x32x16_bf16(mf, qv[kk], acc, 0, 0, 0);
    }

    // guarded in-register top-5 update (overlaps prefetch latency)
#pragma unroll
    for (int g = 0; g < 4; ++g) {
      float c0 = acc[4 * g + 0], c1 = acc[4 * g + 1];
      float c2 = acc[4 * g + 2], c3 = acc[4 * g + 3];
      float m01 = fminf(fminf(c0, c1), fminf(c2, c3));
      if (m01 < t4) {
        ins5(c0, t0, t1, t2, t3, t4);
        ins5(c1, t0, t1, t2, t3, t4);
        ins5(c2, t0, t1, t2, t3, t4);
        ins5(c3, t0, t1, t2, t3, t4);
      }
    }
    __syncthreads();   // prefetch drained; Bs[cur] reads done -> next tile
  }

  // merge the 2 lanes holding the same q-col (lane, lane+32)
  {
    float r0 = __shfl_xor(t0, 32), r1 = __shfl_xor(t1, 32), r2 = __shfl_xor(t2, 32),
          r3 = __shfl_xor(t3, 32), r4 = __shfl_xor(t4, 32);
    ins5(r0, t0, t1, t2, t3, t4);
    ins5(r1, t0, t1, t2, t3, t4);
    ins5(r2, t0, t1, t2, t3, t4);
    ins5(r3, t0, t1, t2, t3, t4);
    ins5(r4, t0, t1, t2, t3, t4);
  }
  if (lane < 32) {
    int grow = row0 + wave * 32 + l31;
    float* o = kp + ((size_t)grow * NSPLIT + split) * 5;
    o[0] = t0; o[1] = t1; o[2] = t2; o[3] = t3; o[4] = t4;
  }
}

// ================= fused mid: q row-norms + Mahalanobis =================
template<int C>
DEV void rownorm_dev(const u16* __restrict__ x, float* __restrict__ out, int bid, int tid) {
  int row = bid * 4 + (tid >> 6);
  int lane = tid & 63;
  constexpr int E = C / 64;
  const u16* p = x + (size_t)row * C + lane * E;
  float s = 0.f;
#pragma unroll
  for (int i = 0; i < E; ++i) { float v = bf2f(p[i]); s += v * v; }
#pragma unroll
  for (int m = 1; m < 64; m <<= 1) s += __shfl_xor(s, m);
  if (lane == 0) out[row] = s;
}

template<int C>
DEV void maha_dev(const u16* __restrict__ qfb, const float* __restrict__ mu,
                  const u16* __restrict__ icovb, float* __restrict__ mh,
                  u16* As, float* muS, int bid, int tid) {
  constexpr int QT = 64, KCH = C / 8;
  int wave = tid >> 6, lane = tid & 63;
  int row0 = bid * QT;

  for (int i = tid; i < C; i += 256) muS[i] = mu[i];
  __syncthreads();
  for (int u = tid; u < QT * KCH; u += 256) {
    int r = u / KCH, cc = u % KCH;
    bf8v v = *(const bf8v*)(qfb + (size_t)(row0 + r) * C + cc * 8);
    s8v d;
#pragma unroll
    for (int i = 0; i < 8; ++i) d[i] = (short)f2bf((float)v[i] - muS[cc * 8 + i]);
    *(s8v*)(As + r * C + ((cc ^ (r & 7)) << 3)) = d;
  }
  __syncthreads();

  int arow = wave * 16 + (lane & 15);
  int kb = lane >> 4;
  float mm[4] = {0.f, 0.f, 0.f, 0.f};
#pragma unroll
  for (int cb = 0; cb < C / 16; ++cb) {
    f4v acc = (f4v){0.f, 0.f, 0.f, 0.f};
    int bcol = cb * 16 + (lane & 15);
#pragma unroll
    for (int kk = 0; kk < C / 32; ++kk) {
      int kc = kk * 4 + kb;
      bf8v a = *(const bf8v*)(As + arow * C + ((kc ^ (arow & 7)) << 3));
      bf8v b = *(const bf8v*)(icovb + (size_t)bcol * C + kc * 8);  // global, L2-hot
      acc = __builtin_amdgcn_mfma_f32_16x16x32_bf16(a, b, acc, 0, 0, 0);
    }
#pragma unroll
    for (int r = 0; r < 4; ++r) {
      int row = wave * 16 + (lane >> 4) * 4 + r;
      int col = cb * 16 + (lane & 15);
      float dv = bf2f(As[row * C + (((col >> 3) ^ (row & 7)) << 3) + (col & 7)]);
      mm[r] += acc[r] * dv;
    }
  }
#pragma unroll
  for (int r = 0; r < 4; ++r) {
    float v = mm[r];
    v += __shfl_xor(v, 1); v += __shfl_xor(v, 2);
    v += __shfl_xor(v, 4); v += __shfl_xor(v, 8);
    if ((lane & 15) == 0)
      mh[row0 + wave * 16 + (lane >> 4) * 4 + r] = sqrtf(fmaxf(v, EPSF));
  }
}

__global__ __launch_bounds__(256) void k_mid(
    const u16* __restrict__ qf2b, const u16* __restrict__ qf3b,
    const float* __restrict__ mean2, const float* __restrict__ mean3,
    const u16* __restrict__ ic2b, const u16* __restrict__ ic3b,
    float* __restrict__ qn2, float* __restrict__ qn3,
    float* __restrict__ mh2, float* __restrict__ mh3) {
  __shared__ alignas(16) u16 As[64 * 256];
  __shared__ float muS[256];
  int bid = blockIdx.x, tid = threadIdx.x;
  if (bid < 3136)       rownorm_dev<128>(qf2b, qn2, bid, tid);
  else if (bid < 6272)  rownorm_dev<256>(qf3b, qn3, bid - 3136, tid);
  else if (bid < 6468)  maha_dev<128>(qf2b, mean2, ic2b, mh2, As, muS, bid - 6272, tid);
  else                  maha_dev<256>(qf3b, mean3, ic3b, mh3, As, muS, bid - 6468, tid);
}

// ================= combine: merge knn splits (+qn), build maps =================
template<int S>
DEV float knn_merge(const float* kp, int n, float qv) {
  float t0 = 1e30f, t1 = 1e30f, t2 = 1e30f, t3 = 1e30f, t4 = 1e30f;
  const float* p = kp + (size_t)n * S * 5;
#pragma unroll
  for (int i = 0; i < S * 5; ++i) ins5(p[i], t0, t1, t2, t3, t4);
  return 0.2f * (sqrtf(fmaxf(t0 + qv, EPSF)) + sqrtf(fmaxf(t1 + qv, EPSF)) +
                 sqrtf(fmaxf(t2 + qv, EPSF)) + sqrtf(fmaxf(t3 + qv, EPSF)) +
                 sqrtf(fmaxf(t4 + qv, EPSF)));
}

__global__ __launch_bounds__(256) void k_combine(
    const float* __restrict__ kp2, const float* __restrict__ kp3,
    const float* __restrict__ qn2, const float* __restrict__ qn3,
    const float* __restrict__ mh2, const float* __restrict__ mh3,
    float* __restrict__ out) {
  int n = blockIdx.x * 256 + threadIdx.x;   // exact: 49*256 == NQ
  float m2v = 0.5f * (knn_merge<16>(kp2, n, qn2[n]) + mh2[n]);
  float m3v = 0.5f * (knn_merge<16>(kp3, n, qn3[n]) + mh3[n]);
  out[16 + n] = 0.5f * (m2v + m3v);
  out[16 + NQ + n] = m2v;
  out[16 + 2 * NQ + n] = m3v;
}

// ================= per-image top-10 mean over 784-pixel map =================
__global__ __launch_bounds__(256) void k_top10(const float* __restrict__ comb, float* __restrict__ pred) {
  __shared__ float vals[1024];
  __shared__ float rv[256];
  __shared__ int ri[256];
  __shared__ float ssum;
  int b = blockIdx.x, tid = threadIdx.x;
  for (int i = tid; i < 1024; i += 256) vals[i] = (i < PP) ? comb[b * PP + i] : -1e30f;
  if (tid == 0) ssum = 0.f;
  __syncthreads();
  for (int it = 0; it < 10; ++it) {
    float bv = -1e30f; int bi = 0;
    for (int i = tid; i < 1024; i += 256) { float v = vals[i]; if (v > bv) { bv = v; bi = i; } }
    rv[tid] = bv; ri[tid] = bi;
    __syncthreads();
    for (int s = 128; s; s >>= 1) {
      if (tid < s && rv[tid + s] > rv[tid]) { rv[tid] = rv[tid + s]; ri[tid] = ri[tid + s]; }
      __syncthreads();
    }
    if (tid == 0) { ssum += rv[0]; vals[ri[0]] = -1e30f; }
    __syncthreads();
  }
  if (tid == 0) pred[b] = ssum * 0.1f;
}

extern "C" void kernel_launch(void* const* d_in, const int* in_sizes, int n_in,
                              void* d_out, int out_size, void* d_ws, size_t ws_size,
                              hipStream_t stream) {
  const float* q2    = (const float*)d_in[0];
  const float* q3    = (const float*)d_in[1];
  const float* mem2  = (const float*)d_in[2];
  const float* mem3  = (const float*)d_in[3];
  const float* mean2 = (const float*)d_in[4];
  const float* mean3 = (const float*)d_in[5];
  const float* icov2 = (const float*)d_in[6];
  const float* icov3 = (const float*)d_in[7];
  float* out = (float*)d_out;

  char* w = (char*)d_ws;
  auto alloc = [&](size_t bytes) { void* p = (void*)w; w += (bytes + 255) & ~(size_t)255; return p; };
  u16* qf2b = (u16*)alloc((size_t)NQ * 128 * 2);
  u16* qf3b = (u16*)alloc((size_t)NQ * 256 * 2);
  u16* m2t  = (u16*)alloc((size_t)MM * 128 * 2);
  u16* m3t  = (u16*)alloc((size_t)MM * 256 * 2);
  u16* ic2b = (u16*)alloc((size_t)128 * 128 * 2);
  u16* ic3b = (u16*)alloc((size_t)256 * 256 * 2);
  float* qn2 = (float*)alloc((size_t)NQ * 4);
  float* qn3 = (float*)alloc((size_t)NQ * 4);
  float* mn2 = (float*)alloc((size_t)MM * 4);
  float* mn3 = (float*)alloc((size_t)MM * 4);
  float* kp2 = (float*)alloc((size_t)NQ * 16 * 5 * 4);
  float* kp3 = (float*)alloc((size_t)NQ * 16 * 5 * 4);
  float* mh2 = (float*)alloc((size_t)NQ * 4);
  float* mh3 = (float*)alloc((size_t)NQ * 4);

  // fused prep: pack_mem2(2048) | pack_mem3(2048) | icov2(8) | icov3(32) | pack_q2(784) | pack_q3(1568)
  k_prep<<<6488, 256, 0, stream>>>(q2, q3, mem2, mem3, icov2, icov3,
                                   qf2b, qf3b, m2t, m3t, ic2b, ic3b, mn2, mn3);

  // 8-wave blocks, 784 each (49 rt x 16 splits).
  // C=256: VGPR~110 -> (512,4): 2 blocks/CU; C=128: VGPR~75 -> (512,6): 3 blocks/CU
  k_score<256, 16, 4><<<784, 512, 0, stream>>>(qf3b, m3t, mn3, kp3);
  k_score<128, 16, 6><<<784, 512, 0, stream>>>(qf2b, m2t, mn2, kp2);

  // fused mid: rownorm_q2(3136) | rownorm_q3(3136) | maha128(196) | maha256(196)
  k_mid<<<6664, 256, 0, stream>>>(qf2b, qf3b, mean2, mean3, ic2b, ic3b, qn2, qn3, mh2, mh3);

  k_combine<<<NQ / 256, 256, 0, stream>>>(kp2, kp3, qn2, qn3, mh2, mh3, out);
  k_top10<<<16, 256, 0, stream>>>(out + 16, out);

  (void)in_sizes; (void)n_in; (void)out_size; (void)ws_size;
}

// Round 10
// 232.540 us; speedup vs baseline: 1.0997x; 1.0198x over previous
//
#include <hip/hip_runtime.h>

typedef unsigned short u16;
typedef unsigned int u32;
typedef __attribute__((ext_vector_type(8))) __bf16 bf8v;    // MFMA A/B operand (8 bf16)
typedef __attribute__((ext_vector_type(8))) short s8v;      // same bits, for packing
typedef __attribute__((ext_vector_type(4))) float f4v;
typedef __attribute__((ext_vector_type(16))) float f16v;    // 32x32 MFMA C/D

#define DEV static __device__ __forceinline__

constexpr int NQ = 12544;   // B*H*W = 16*28*28
constexpr int MM = 8192;    // memory bank rows
constexpr int PP = 784;     // H*W
constexpr float EPSF = 1e-12f;

DEV u16 f2bf(float f) {  // RNE f32 -> bf16 (inputs are finite normals)
  u32 u = __float_as_uint(f);
  return (u16)((u + 0x7FFFu + ((u >> 16) & 1u)) >> 16);
}
DEV float bf2f(u16 h) { return __uint_as_float((u32)h << 16); }

DEV void gl2lds16(const u16* g, u16* l) {
  __builtin_amdgcn_global_load_lds(
      (const __attribute__((address_space(1))) unsigned int*)(g),
      (__attribute__((address_space(3))) unsigned int*)(l), 16, 0, 0);
}
DEV void gl2lds4(const float* g, float* l) {
  __builtin_amdgcn_global_load_lds(
      (const __attribute__((address_space(1))) unsigned int*)(g),
      (__attribute__((address_space(3))) unsigned int*)(l), 4, 0, 0);
}

template<int N> DEV void wait_vm() {   // counted vmcnt (T4): literal immediates only
  if constexpr (N == 0) asm volatile("s_waitcnt vmcnt(0)" ::: "memory");
  else if constexpr (N == 2) asm volatile("s_waitcnt vmcnt(2)" ::: "memory");
  else if constexpr (N == 3) asm volatile("s_waitcnt vmcnt(3)" ::: "memory");
  else if constexpr (N == 4) asm volatile("s_waitcnt vmcnt(4)" ::: "memory");
  else if constexpr (N == 6) asm volatile("s_waitcnt vmcnt(6)" ::: "memory");
  else static_assert(N == 0, "unsupported vmcnt");
}

// branchless sorted insert: keep 5 smallest in a0<=..<=a4
DEV void ins5(float v, float& a0, float& a1, float& a2, float& a3, float& a4) {
  float hi;
  hi = fmaxf(v, a0); a0 = fminf(v, a0); v = hi;
  hi = fmaxf(v, a1); a1 = fminf(v, a1); v = hi;
  hi = fmaxf(v, a2); a2 = fminf(v, a2); v = hi;
  hi = fmaxf(v, a3); a3 = fminf(v, a3); v = hi;
  a4 = fminf(v, a4);
}

// ================= fused prep =================
DEV void pack_bf16_dev(const float* __restrict__ x, u16* __restrict__ y, int bid, int tid) {
  int g = bid * 256 + tid;
  const float4* px = (const float4*)x + (size_t)g * 2;
  float4 a = px[0], b = px[1];
  s8v o;
  o[0] = (short)f2bf(a.x); o[1] = (short)f2bf(a.y); o[2] = (short)f2bf(a.z); o[3] = (short)f2bf(a.w);
  o[4] = (short)f2bf(b.x); o[5] = (short)f2bf(b.y); o[6] = (short)f2bf(b.z); o[7] = (short)f2bf(b.w);
  ((s8v*)y)[g] = o;
}

// mem pack: store -2*m (exact bf16 scale) K-MAJOR in global: yT[chunk][row][8]
template<int C>
DEV void pack_mem_dev(const float* __restrict__ x, u16* __restrict__ yT, float* __restrict__ nrm,
                      int bid, int tid) {
  int row = bid * 4 + (tid >> 6), lane = tid & 63;
  constexpr int E = C / 64;
  const float* src = x + (size_t)row * C + lane * E;
  float s = 0.f;
  if constexpr (E == 4) {
    float4 v = *(const float4*)src;
    s = v.x * v.x + v.y * v.y + v.z * v.z + v.w * v.w;
    u32 lo = (u32)f2bf(-2.f * v.x) | ((u32)f2bf(-2.f * v.y) << 16);
    u32 hi = (u32)f2bf(-2.f * v.z) | ((u32)f2bf(-2.f * v.w) << 16);
    size_t di = ((size_t)(lane >> 1) * MM + row) * 8 + (lane & 1) * 4;
    *(uint2*)(yT + di) = make_uint2(lo, hi);
  } else {
    float2 v = *(const float2*)src;
    s = v.x * v.x + v.y * v.y;
    size_t di = ((size_t)(lane >> 2) * MM + row) * 8 + (lane & 3) * 2;
    *(u32*)(yT + di) = (u32)f2bf(-2.f * v.x) | ((u32)f2bf(-2.f * v.y) << 16);
  }
#pragma unroll
  for (int m = 1; m < 64; m <<= 1) s += __shfl_xor(s, m);
  if (lane == 0) nrm[row] = s;
}

template<int C>
DEV void pack_q_dev(const float* __restrict__ q, u16* __restrict__ qfb, int bid, int tid) {
  int g = bid * 256 + tid;
  int n = g % NQ;
  int cc = g / NQ;
  int b = n / PP, p = n % PP;
  int c0 = cc * 8;
  const float* src = q + ((size_t)b * C + c0) * PP + p;
  s8v o;
#pragma unroll
  for (int i = 0; i < 8; ++i) o[i] = (short)f2bf(src[(size_t)i * PP]);
  ((s8v*)qfb)[((size_t)n * C + c0) >> 3] = o;
}

__global__ __launch_bounds__(256) void k_prep(
    const float* __restrict__ q2, const float* __restrict__ q3,
    const float* __restrict__ mem2, const float* __restrict__ mem3,
    const float* __restrict__ icov2, const float* __restrict__ icov3,
    u16* __restrict__ qf2b, u16* __restrict__ qf3b,
    u16* __restrict__ m2t, u16* __restrict__ m3t,
    u16* __restrict__ ic2b, u16* __restrict__ ic3b,
    float* __restrict__ mn2, float* __restrict__ mn3) {
  int bid = blockIdx.x, tid = threadIdx.x;
  if (bid < 2048)       pack_mem_dev<128>(mem2, m2t, mn2, bid, tid);
  else if (bid < 4096)  pack_mem_dev<256>(mem3, m3t, mn3, bid - 2048, tid);
  else if (bid < 4104)  pack_bf16_dev(icov2, ic2b, bid - 4096, tid);
  else if (bid < 4136)  pack_bf16_dev(icov3, ic3b, bid - 4104, tid);
  else if (bid < 4920)  pack_q_dev<128>(q2, qf2b, bid - 4136, tid);
  else                  pack_q_dev<256>(q3, qf3b, bid - 4920, tid);
}

// ================= fused distances + per-row 5 smallest d2' =================
// 32x32x16 MFMA, K-major LDS, in-register top-5 (R9 structure) + T3/T4 pipeline:
// 3 LDS buffers, counted s_waitcnt vmcnt(2P) + RAW s_barrier (no drain) -> 2 tiles
// of global_load_lds stay in flight across barriers; miss latency hidden.
// Per-wave loads/tile uniform: P = SIT + 1 (all waves dup-load mn; identical-write benign).
template<int C, int NSPLIT, int WPEU>
__global__ __launch_bounds__(512, WPEU)
void k_score(const u16* __restrict__ qf, const u16* __restrict__ memT,
             const float* __restrict__ mn, float* __restrict__ kp) {
  constexpr int MT = 32, MS = MM / NSPLIT, NT = MS / MT;
  constexpr int CHUNKS = C / 8;
  constexpr int SIT = CHUNKS / 16;        // 16B gl2lds per wave per tile (2 @C=256, 1 @C=128)
  constexpr int P = SIT + 1;              // + mn load
  constexpr int QROWS = 8 * 32;
  constexpr int RT = NQ / QROWS;          // 49
  static_assert(NT >= 4, "pipeline needs NT>=4");
  __shared__ alignas(16) u16 Bs[3][CHUNKS * MT * 8];
  __shared__ alignas(16) float mnS[3][64];

  const int tid = threadIdx.x, wave = tid >> 6, lane = tid & 63;
  const int l31 = lane & 31, kh = lane >> 5;
  const int rt = blockIdx.x % RT, split = blockIdx.x / RT;
  const int row0 = rt * QROWS, mb0 = split * MS;

  // q fragments (B operand; loop-invariant) -> registers, pinned.
  bf8v qv[C / 16];
#pragma unroll
  for (int kk = 0; kk < C / 16; ++kk)
    qv[kk] = *(const bf8v*)(qf + (size_t)(row0 + wave * 32 + l31) * C + kk * 16 + kh * 8);
#pragma unroll
  for (int kk = 0; kk < C / 16; ++kk)
    asm volatile("" : "+v"(qv[kk]));

  auto STAGE = [&](int buf, int t) {   // exactly P vmem ops per wave
    const int mrow0 = mb0 + t * MT;
#pragma unroll
    for (int it = 0; it < SIT; ++it) {
      int cp2 = wave + it * 8;
      gl2lds16(memT + ((size_t)(cp2 * 2 + kh) * MM + mrow0 + l31) * 8,
               Bs[buf] + cp2 * 512 + lane * 8);
    }
    gl2lds4(mn + mrow0 + lane, &mnS[buf][0] + lane);   // dup across waves: benign
  };

  float t0 = 1e30f, t1 = 1e30f, t2 = 1e30f, t3 = 1e30f, t4 = 1e30f;

  auto COMPUTE = [&](int cur) {
    f16v acc;
#pragma unroll
    for (int g = 0; g < 4; ++g) {
      f4v m4 = *(const f4v*)(&mnS[cur][0] + g * 8 + kh * 4);
      acc[4 * g + 0] = m4[0]; acc[4 * g + 1] = m4[1];
      acc[4 * g + 2] = m4[2]; acc[4 * g + 3] = m4[3];
    }
    const u16* Bb = Bs[cur] + l31 * 8 + kh * 256;
#pragma unroll
    for (int kk = 0; kk < C / 16; ++kk) {
      bf8v mf = *(const bf8v*)(Bb + kk * 512);
      acc = __builtin_amdgcn_mfma_f32_32x32x16_bf16(mf, qv[kk], acc, 0, 0, 0);
    }
#pragma unroll
    for (int g = 0; g < 4; ++g) {
      float c0 = acc[4 * g + 0], c1 = acc[4 * g + 1];
      float c2 = acc[4 * g + 2], c3 = acc[4 * g + 3];
      float m01 = fminf(fminf(c0, c1), fminf(c2, c3));
      if (m01 < t4) {
        ins5(c0, t0, t1, t2, t3, t4);
        ins5(c1, t0, t1, t2, t3, t4);
        ins5(c2, t0, t1, t2, t3, t4);
        ins5(c3, t0, t1, t2, t3, t4);
      }
    }
  };

  // prologue: 3 tiles in flight (3P outstanding per wave)
  STAGE(0, 0); STAGE(1, 1); STAGE(2, 2);

  // steady state: wait vmcnt(2P) -> tile t landed, t+1/t+2 still flying
  for (int t = 0; t < NT - 3; ++t) {
    const int cur = t % 3;
    wait_vm<2 * P>();
    __builtin_amdgcn_sched_barrier(0);
    __builtin_amdgcn_s_barrier();
    __builtin_amdgcn_sched_barrier(0);
    COMPUTE(cur);
    __builtin_amdgcn_sched_barrier(0);
    __builtin_amdgcn_s_barrier();      // all waves done reading Bs[cur]
    __builtin_amdgcn_sched_barrier(0);
    STAGE(cur, t + 3);                 // refill freed buffer (outstanding back to 3P)
  }
  // tail: t = NT-3 (2P outstanding after wait), NT-2 (P), NT-1 (0)
  {
    wait_vm<2 * P>();
    __builtin_amdgcn_sched_barrier(0);
    __builtin_amdgcn_s_barrier();
    __builtin_amdgcn_sched_barrier(0);
    COMPUTE((NT - 3) % 3);
    __builtin_amdgcn_sched_barrier(0);
    __builtin_amdgcn_s_barrier();
    wait_vm<P>();
    __builtin_amdgcn_sched_barrier(0);
    __builtin_amdgcn_s_barrier();
    __builtin_amdgcn_sched_barrier(0);
    COMPUTE((NT - 2) % 3);
    __builtin_amdgcn_sched_barrier(0);
    __builtin_amdgcn_s_barrier();
    wait_vm<0>();
    __builtin_amdgcn_sched_barrier(0);
    __builtin_amdgcn_s_barrier();
    __builtin_amdgcn_sched_barrier(0);
    COMPUTE((NT - 1) % 3);
  }

  // merge the 2 lanes holding the same q-col (lane, lane+32)
  {
    float r0 = __shfl_xor(t0, 32), r1 = __shfl_xor(t1, 32), r2 = __shfl_xor(t2, 32),
          r3 = __shfl_xor(t3, 32), r4 = __shfl_xor(t4, 32);
    ins5(r0, t0, t1, t2, t3, t4);
    ins5(r1, t0, t1, t2, t3, t4);
    ins5(r2, t0, t1, t2, t3, t4);
    ins5(r3, t0, t1, t2, t3, t4);
    ins5(r4, t0, t1, t2, t3, t4);
  }
  if (lane < 32) {
    int grow = row0 + wave * 32 + l31;
    float* o = kp + ((size_t)grow * NSPLIT + split) * 5;
    o[0] = t0; o[1] = t1; o[2] = t2; o[3] = t3; o[4] = t4;
  }
}

// ================= fused mid: q row-norms + Mahalanobis =================
template<int C>
DEV void rownorm_dev(const u16* __restrict__ x, float* __restrict__ out, int bid, int tid) {
  int row = bid * 4 + (tid >> 6);
  int lane = tid & 63;
  constexpr int E = C / 64;
  const u16* p = x + (size_t)row * C + lane * E;
  float s = 0.f;
#pragma unroll
  for (int i = 0; i < E; ++i) { float v = bf2f(p[i]); s += v * v; }
#pragma unroll
  for (int m = 1; m < 64; m <<= 1) s += __shfl_xor(s, m);
  if (lane == 0) out[row] = s;
}

template<int C>
DEV void maha_dev(const u16* __restrict__ qfb, const float* __restrict__ mu,
                  const u16* __restrict__ icovb, float* __restrict__ mh,
                  u16* As, float* muS, int bid, int tid) {
  constexpr int QT = 64, KCH = C / 8;
  int wave = tid >> 6, lane = tid & 63;
  int row0 = bid * QT;

  for (int i = tid; i < C; i += 256) muS[i] = mu[i];
  __syncthreads();
  for (int u = tid; u < QT * KCH; u += 256) {
    int r = u / KCH, cc = u % KCH;
    bf8v v = *(const bf8v*)(qfb + (size_t)(row0 + r) * C + cc * 8);
    s8v d;
#pragma unroll
    for (int i = 0; i < 8; ++i) d[i] = (short)f2bf((float)v[i] - muS[cc * 8 + i]);
    *(s8v*)(As + r * C + ((cc ^ (r & 7)) << 3)) = d;
  }
  __syncthreads();

  int arow = wave * 16 + (lane & 15);
  int kb = lane >> 4;
  float mm[4] = {0.f, 0.f, 0.f, 0.f};
#pragma unroll
  for (int cb = 0; cb < C / 16; ++cb) {
    f4v acc = (f4v){0.f, 0.f, 0.f, 0.f};
    int bcol = cb * 16 + (lane & 15);
#pragma unroll
    for (int kk = 0; kk < C / 32; ++kk) {
      int kc = kk * 4 + kb;
      bf8v a = *(const bf8v*)(As + arow * C + ((kc ^ (arow & 7)) << 3));
      bf8v b = *(const bf8v*)(icovb + (size_t)bcol * C + kc * 8);
      acc = __builtin_amdgcn_mfma_f32_16x16x32_bf16(a, b, acc, 0, 0, 0);
    }
#pragma unroll
    for (int r = 0; r < 4; ++r) {
      int row = wave * 16 + (lane >> 4) * 4 + r;
      int col = cb * 16 + (lane & 15);
      float dv = bf2f(As[row * C + (((col >> 3) ^ (row & 7)) << 3) + (col & 7)]);
      mm[r] += acc[r] * dv;
    }
  }
#pragma unroll
  for (int r = 0; r < 4; ++r) {
    float v = mm[r];
    v += __shfl_xor(v, 1); v += __shfl_xor(v, 2);
    v += __shfl_xor(v, 4); v += __shfl_xor(v, 8);
    if ((lane & 15) == 0)
      mh[row0 + wave * 16 + (lane >> 4) * 4 + r] = sqrtf(fmaxf(v, EPSF));
  }
}

__global__ __launch_bounds__(256) void k_mid(
    const u16* __restrict__ qf2b, const u16* __restrict__ qf3b,
    const float* __restrict__ mean2, const float* __restrict__ mean3,
    const u16* __restrict__ ic2b, const u16* __restrict__ ic3b,
    float* __restrict__ qn2, float* __restrict__ qn3,
    float* __restrict__ mh2, float* __restrict__ mh3) {
  __shared__ alignas(16) u16 As[64 * 256];
  __shared__ float muS[256];
  int bid = blockIdx.x, tid = threadIdx.x;
  if (bid < 3136)       rownorm_dev<128>(qf2b, qn2, bid, tid);
  else if (bid < 6272)  rownorm_dev<256>(qf3b, qn3, bid - 3136, tid);
  else if (bid < 6468)  maha_dev<128>(qf2b, mean2, ic2b, mh2, As, muS, bid - 6272, tid);
  else                  maha_dev<256>(qf3b, mean3, ic3b, mh3, As, muS, bid - 6468, tid);
}

// ================= combine: merge knn splits (+qn), build maps =================
template<int S>
DEV float knn_merge(const float* kp, int n, float qv) {
  float t0 = 1e30f, t1 = 1e30f, t2 = 1e30f, t3 = 1e30f, t4 = 1e30f;
  const float* p = kp + (size_t)n * S * 5;
#pragma unroll
  for (int i = 0; i < S * 5; ++i) ins5(p[i], t0, t1, t2, t3, t4);
  return 0.2f * (sqrtf(fmaxf(t0 + qv, EPSF)) + sqrtf(fmaxf(t1 + qv, EPSF)) +
                 sqrtf(fmaxf(t2 + qv, EPSF)) + sqrtf(fmaxf(t3 + qv, EPSF)) +
                 sqrtf(fmaxf(t4 + qv, EPSF)));
}

__global__ __launch_bounds__(256) void k_combine(
    const float* __restrict__ kp2, const float* __restrict__ kp3,
    const float* __restrict__ qn2, const float* __restrict__ qn3,
    const float* __restrict__ mh2, const float* __restrict__ mh3,
    float* __restrict__ out) {
  int n = blockIdx.x * 256 + threadIdx.x;
  float m2v = 0.5f * (knn_merge<16>(kp2, n, qn2[n]) + mh2[n]);
  float m3v = 0.5f * (knn_merge<16>(kp3, n, qn3[n]) + mh3[n]);
  out[16 + n] = 0.5f * (m2v + m3v);
  out[16 + NQ + n] = m2v;
  out[16 + 2 * NQ + n] = m3v;
}

// ================= per-image top-10 mean over 784-pixel map =================
__global__ __launch_bounds__(256) void k_top10(const float* __restrict__ comb, float* __restrict__ pred) {
  __shared__ float vals[1024];
  __shared__ float rv[256];
  __shared__ int ri[256];
  __shared__ float ssum;
  int b = blockIdx.x, tid = threadIdx.x;
  for (int i = tid; i < 1024; i += 256) vals[i] = (i < PP) ? comb[b * PP + i] : -1e30f;
  if (tid == 0) ssum = 0.f;
  __syncthreads();
  for (int it = 0; it < 10; ++it) {
    float bv = -1e30f; int bi = 0;
    for (int i = tid; i < 1024; i += 256) { float v = vals[i]; if (v > bv) { bv = v; bi = i; } }
    rv[tid] = bv; ri[tid] = bi;
    __syncthreads();
    for (int s = 128; s; s >>= 1) {
      if (tid < s && rv[tid + s] > rv[tid]) { rv[tid] = rv[tid + s]; ri[tid] = ri[tid + s]; }
      __syncthreads();
    }
    if (tid == 0) { ssum += rv[0]; vals[ri[0]] = -1e30f; }
    __syncthreads();
  }
  if (tid == 0) pred[b] = ssum * 0.1f;
}

extern "C" void kernel_launch(void* const* d_in, const int* in_sizes, int n_in,
                              void* d_out, int out_size, void* d_ws, size_t ws_size,
                              hipStream_t stream) {
  const float* q2    = (const float*)d_in[0];
  const float* q3    = (const float*)d_in[1];
  const float* mem2  = (const float*)d_in[2];
  const float* mem3  = (const float*)d_in[3];
  const float* mean2 = (const float*)d_in[4];
  const float* mean3 = (const float*)d_in[5];
  const float* icov2 = (const float*)d_in[6];
  const float* icov3 = (const float*)d_in[7];
  float* out = (float*)d_out;

  char* w = (char*)d_ws;
  auto alloc = [&](size_t bytes) { void* p = (void*)w; w += (bytes + 255) & ~(size_t)255; return p; };
  u16* qf2b = (u16*)alloc((size_t)NQ * 128 * 2);
  u16* qf3b = (u16*)alloc((size_t)NQ * 256 * 2);
  u16* m2t  = (u16*)alloc((size_t)MM * 128 * 2);
  u16* m3t  = (u16*)alloc((size_t)MM * 256 * 2);
  u16* ic2b = (u16*)alloc((size_t)128 * 128 * 2);
  u16* ic3b = (u16*)alloc((size_t)256 * 256 * 2);
  float* qn2 = (float*)alloc((size_t)NQ * 4);
  float* qn3 = (float*)alloc((size_t)NQ * 4);
  float* mn2 = (float*)alloc((size_t)MM * 4);
  float* mn3 = (float*)alloc((size_t)MM * 4);
  float* kp2 = (float*)alloc((size_t)NQ * 16 * 5 * 4);
  float* kp3 = (float*)alloc((size_t)NQ * 16 * 5 * 4);
  float* mh2 = (float*)alloc((size_t)NQ * 4);
  float* mh3 = (float*)alloc((size_t)NQ * 4);

  k_prep<<<6488, 256, 0, stream>>>(q2, q3, mem2, mem3, icov2, icov3,
                                   qf2b, qf3b, m2t, m3t, ic2b, ic3b, mn2, mn3);

  // 784 blocks (49 rt x 16 splits), 8 waves, 3-buffer counted-vmcnt pipeline
  k_score<256, 16, 4><<<784, 512, 0, stream>>>(qf3b, m3t, mn3, kp3);
  k_score<128, 16, 6><<<784, 512, 0, stream>>>(qf2b, m2t, mn2, kp2);

  k_mid<<<6664, 256, 0, stream>>>(qf2b, qf3b, mean2, mean3, ic2b, ic3b, qn2, qn3, mh2, mh3);

  k_combine<<<NQ / 256, 256, 0, stream>>>(kp2, kp3, qn2, qn3, mh2, mh3, out);
  k_top10<<<16, 256, 0, stream>>>(out + 16, out);

  (void)in_sizes; (void)n_in; (void)out_size; (void)ws_size;
}

// Round 11
// 232.411 us; speedup vs baseline: 1.1003x; 1.0006x over previous
//
#include <hip/hip_runtime.h>

typedef unsigned short u16;
typedef unsigned int u32;
typedef __attribute__((ext_vector_type(8))) __bf16 bf8v;    // MFMA A/B operand (8 bf16)
typedef __attribute__((ext_vector_type(8))) short s8v;      // same bits, for packing
typedef __attribute__((ext_vector_type(4))) float f4v;
typedef __attribute__((ext_vector_type(16))) float f16v;    // 32x32 MFMA C/D

#define DEV static __device__ __forceinline__

constexpr int NQ = 12544;   // B*H*W = 16*28*28
constexpr int MM = 8192;    // memory bank rows
constexpr int PP = 784;     // H*W
constexpr float EPSF = 1e-12f;

DEV u16 f2bf(float f) {  // RNE f32 -> bf16 (inputs are finite normals)
  u32 u = __float_as_uint(f);
  return (u16)((u + 0x7FFFu + ((u >> 16) & 1u)) >> 16);
}
DEV float bf2f(u16 h) { return __uint_as_float((u32)h << 16); }

DEV void gl2lds16(const u16* g, u16* l) {
  __builtin_amdgcn_global_load_lds(
      (const __attribute__((address_space(1))) unsigned int*)(g),
      (__attribute__((address_space(3))) unsigned int*)(l), 16, 0, 0);
}
DEV void gl2lds4(const float* g, float* l) {
  __builtin_amdgcn_global_load_lds(
      (const __attribute__((address_space(1))) unsigned int*)(g),
      (__attribute__((address_space(3))) unsigned int*)(l), 4, 0, 0);
}

template<int N> DEV void wait_vm() {   // counted vmcnt (T4): literal immediates only
  if constexpr (N == 0) asm volatile("s_waitcnt vmcnt(0)" ::: "memory");
  else if constexpr (N == 2) asm volatile("s_waitcnt vmcnt(2)" ::: "memory");
  else if constexpr (N == 3) asm volatile("s_waitcnt vmcnt(3)" ::: "memory");
  else if constexpr (N == 4) asm volatile("s_waitcnt vmcnt(4)" ::: "memory");
  else if constexpr (N == 6) asm volatile("s_waitcnt vmcnt(6)" ::: "memory");
  else static_assert(N == 0, "unsupported vmcnt");
}

// branchless sorted insert: keep 5 smallest in a0<=..<=a4
DEV void ins5(float v, float& a0, float& a1, float& a2, float& a3, float& a4) {
  float hi;
  hi = fmaxf(v, a0); a0 = fminf(v, a0); v = hi;
  hi = fmaxf(v, a1); a1 = fminf(v, a1); v = hi;
  hi = fmaxf(v, a2); a2 = fminf(v, a2); v = hi;
  hi = fmaxf(v, a3); a3 = fminf(v, a3); v = hi;
  a4 = fminf(v, a4);
}

// ================= fused prep =================
DEV void pack_bf16_dev(const float* __restrict__ x, u16* __restrict__ y, int bid, int tid) {
  int g = bid * 256 + tid;
  const float4* px = (const float4*)x + (size_t)g * 2;
  float4 a = px[0], b = px[1];
  s8v o;
  o[0] = (short)f2bf(a.x); o[1] = (short)f2bf(a.y); o[2] = (short)f2bf(a.z); o[3] = (short)f2bf(a.w);
  o[4] = (short)f2bf(b.x); o[5] = (short)f2bf(b.y); o[6] = (short)f2bf(b.z); o[7] = (short)f2bf(b.w);
  ((s8v*)y)[g] = o;
}

// mem pack: store -2*m (exact bf16 scale) K-MAJOR in global: yT[chunk][row][8]
template<int C>
DEV void pack_mem_dev(const float* __restrict__ x, u16* __restrict__ yT, float* __restrict__ nrm,
                      int bid, int tid) {
  int row = bid * 4 + (tid >> 6), lane = tid & 63;
  constexpr int E = C / 64;
  const float* src = x + (size_t)row * C + lane * E;
  float s = 0.f;
  if constexpr (E == 4) {
    float4 v = *(const float4*)src;
    s = v.x * v.x + v.y * v.y + v.z * v.z + v.w * v.w;
    u32 lo = (u32)f2bf(-2.f * v.x) | ((u32)f2bf(-2.f * v.y) << 16);
    u32 hi = (u32)f2bf(-2.f * v.z) | ((u32)f2bf(-2.f * v.w) << 16);
    size_t di = ((size_t)(lane >> 1) * MM + row) * 8 + (lane & 1) * 4;
    *(uint2*)(yT + di) = make_uint2(lo, hi);
  } else {
    float2 v = *(const float2*)src;
    s = v.x * v.x + v.y * v.y;
    size_t di = ((size_t)(lane >> 2) * MM + row) * 8 + (lane & 3) * 2;
    *(u32*)(yT + di) = (u32)f2bf(-2.f * v.x) | ((u32)f2bf(-2.f * v.y) << 16);
  }
#pragma unroll
  for (int m = 1; m < 64; m <<= 1) s += __shfl_xor(s, m);
  if (lane == 0) nrm[row] = s;
}

template<int C>
DEV void pack_q_dev(const float* __restrict__ q, u16* __restrict__ qfb, int bid, int tid) {
  int g = bid * 256 + tid;
  int n = g % NQ;
  int cc = g / NQ;
  int b = n / PP, p = n % PP;
  int c0 = cc * 8;
  const float* src = q + ((size_t)b * C + c0) * PP + p;
  s8v o;
#pragma unroll
  for (int i = 0; i < 8; ++i) o[i] = (short)f2bf(src[(size_t)i * PP]);
  ((s8v*)qfb)[((size_t)n * C + c0) >> 3] = o;
}

__global__ __launch_bounds__(256) void k_prep(
    const float* __restrict__ q2, const float* __restrict__ q3,
    const float* __restrict__ mem2, const float* __restrict__ mem3,
    const float* __restrict__ icov2, const float* __restrict__ icov3,
    u16* __restrict__ qf2b, u16* __restrict__ qf3b,
    u16* __restrict__ m2t, u16* __restrict__ m3t,
    u16* __restrict__ ic2b, u16* __restrict__ ic3b,
    float* __restrict__ mn2, float* __restrict__ mn3) {
  int bid = blockIdx.x, tid = threadIdx.x;
  if (bid < 2048)       pack_mem_dev<128>(mem2, m2t, mn2, bid, tid);
  else if (bid < 4096)  pack_mem_dev<256>(mem3, m3t, mn3, bid - 2048, tid);
  else if (bid < 4104)  pack_bf16_dev(icov2, ic2b, bid - 4096, tid);
  else if (bid < 4136)  pack_bf16_dev(icov3, ic3b, bid - 4104, tid);
  else if (bid < 4920)  pack_q_dev<128>(q2, qf2b, bid - 4136, tid);
  else                  pack_q_dev<256>(q3, qf3b, bid - 4920, tid);
}

// ================= fused distances + per-row 5 smallest d2' =================
// 32x32x16 MFMA, K-major LDS, in-register top-5, 3-buffer counted-vmcnt pipeline.
// Shared body for both layers; the fused launcher interleaves C=256 (even bid)
// and C=128 (odd bid) blocks so their fetch/compute phases overlap chip-wide.
template<int C, int NSPLIT>
DEV void score_body(const u16* __restrict__ qf, const u16* __restrict__ memT,
                    const float* __restrict__ mn, float* __restrict__ kp,
                    int bid2, u16* __restrict__ BsB, float* __restrict__ mnSB, int tid) {
  constexpr int MT = 32, MS = MM / NSPLIT, NT = MS / MT;   // NT = 32 for NSPLIT=8
  constexpr int CHUNKS = C / 8;
  constexpr int SIT = CHUNKS / 16;        // 2 @C=256, 1 @C=128
  constexpr int P = SIT + 1;              // + mn load
  constexpr int BSTRIDE = 8192;           // u16 per LDS buffer (sized for C=256)
  constexpr int QROWS = 8 * 32;
  constexpr int RT = NQ / QROWS;          // 49
  static_assert(NT >= 4, "pipeline needs NT>=4");

  const int wave = tid >> 6, lane = tid & 63;
  const int l31 = lane & 31, kh = lane >> 5;
  const int rt = bid2 % RT, split = bid2 / RT;
  const int row0 = rt * QROWS, mb0 = split * MS;

  // q fragments (B operand; loop-invariant) -> registers, pinned.
  bf8v qv[C / 16];
#pragma unroll
  for (int kk = 0; kk < C / 16; ++kk)
    qv[kk] = *(const bf8v*)(qf + (size_t)(row0 + wave * 32 + l31) * C + kk * 16 + kh * 8);
#pragma unroll
  for (int kk = 0; kk < C / 16; ++kk)
    asm volatile("" : "+v"(qv[kk]));

  auto STAGE = [&](int buf, int t) {   // exactly P vmem ops per wave
    const int mrow0 = mb0 + t * MT;
    u16* Bs = BsB + buf * BSTRIDE;
#pragma unroll
    for (int it = 0; it < SIT; ++it) {
      int cp2 = wave + it * 8;
      gl2lds16(memT + ((size_t)(cp2 * 2 + kh) * MM + mrow0 + l31) * 8,
               Bs + cp2 * 512 + lane * 8);
    }
    gl2lds4(mn + mrow0 + (lane & 31), mnSB + buf * 64 + (lane & 31));   // dup: benign
  };

  float t0 = 1e30f, t1 = 1e30f, t2 = 1e30f, t3 = 1e30f, t4 = 1e30f;

  auto COMPUTE = [&](int cur) {
    f16v acc;
#pragma unroll
    for (int g = 0; g < 4; ++g) {
      f4v m4 = *(const f4v*)(mnSB + cur * 64 + g * 8 + kh * 4);
      acc[4 * g + 0] = m4[0]; acc[4 * g + 1] = m4[1];
      acc[4 * g + 2] = m4[2]; acc[4 * g + 3] = m4[3];
    }
    const u16* Bb = BsB + cur * BSTRIDE + l31 * 8 + kh * 256;
#pragma unroll
    for (int kk = 0; kk < C / 16; ++kk) {
      bf8v mf = *(const bf8v*)(Bb + kk * 512);
      acc = __builtin_amdgcn_mfma_f32_32x32x16_bf16(mf, qv[kk], acc, 0, 0, 0);
    }
#pragma unroll
    for (int g = 0; g < 4; ++g) {
      float c0 = acc[4 * g + 0], c1 = acc[4 * g + 1];
      float c2 = acc[4 * g + 2], c3 = acc[4 * g + 3];
      float m01 = fminf(fminf(c0, c1), fminf(c2, c3));
      if (m01 < t4) {
        ins5(c0, t0, t1, t2, t3, t4);
        ins5(c1, t0, t1, t2, t3, t4);
        ins5(c2, t0, t1, t2, t3, t4);
        ins5(c3, t0, t1, t2, t3, t4);
      }
    }
  };

  STAGE(0, 0); STAGE(1, 1); STAGE(2, 2);   // 3 tiles in flight (3P outstanding)

  for (int t = 0; t < NT - 3; ++t) {
    const int cur = t % 3;
    wait_vm<2 * P>();
    __builtin_amdgcn_sched_barrier(0);
    __builtin_amdgcn_s_barrier();
    __builtin_amdgcn_sched_barrier(0);
    COMPUTE(cur);
    __builtin_amdgcn_sched_barrier(0);
    __builtin_amdgcn_s_barrier();      // all waves done reading Bs[cur]
    __builtin_amdgcn_sched_barrier(0);
    STAGE(cur, t + 3);
  }
  {
    wait_vm<2 * P>();
    __builtin_amdgcn_sched_barrier(0);
    __builtin_amdgcn_s_barrier();
    __builtin_amdgcn_sched_barrier(0);
    COMPUTE((NT - 3) % 3);
    __builtin_amdgcn_sched_barrier(0);
    __builtin_amdgcn_s_barrier();
    wait_vm<P>();
    __builtin_amdgcn_sched_barrier(0);
    __builtin_amdgcn_s_barrier();
    __builtin_amdgcn_sched_barrier(0);
    COMPUTE((NT - 2) % 3);
    __builtin_amdgcn_sched_barrier(0);
    __builtin_amdgcn_s_barrier();
    wait_vm<0>();
    __builtin_amdgcn_sched_barrier(0);
    __builtin_amdgcn_s_barrier();
    __builtin_amdgcn_sched_barrier(0);
    COMPUTE((NT - 1) % 3);
  }

  // merge the 2 lanes holding the same q-col (lane, lane+32)
  {
    float r0 = __shfl_xor(t0, 32), r1 = __shfl_xor(t1, 32), r2 = __shfl_xor(t2, 32),
          r3 = __shfl_xor(t3, 32), r4 = __shfl_xor(t4, 32);
    ins5(r0, t0, t1, t2, t3, t4);
    ins5(r1, t0, t1, t2, t3, t4);
    ins5(r2, t0, t1, t2, t3, t4);
    ins5(r3, t0, t1, t2, t3, t4);
    ins5(r4, t0, t1, t2, t3, t4);
  }
  if (lane < 32) {
    int grow = row0 + wave * 32 + l31;
    float* o = kp + ((size_t)grow * NSPLIT + split) * 5;
    o[0] = t0; o[1] = t1; o[2] = t2; o[3] = t3; o[4] = t4;
  }
}

// fused launcher: even bid -> C=256 (layer 3), odd bid -> C=128 (layer 2)
__global__ __launch_bounds__(512, 4) void k_score_f(
    const u16* __restrict__ qf3, const u16* __restrict__ m3t,
    const float* __restrict__ mn3, float* __restrict__ kp3,
    const u16* __restrict__ qf2, const u16* __restrict__ m2t,
    const float* __restrict__ mn2, float* __restrict__ kp2) {
  __shared__ alignas(16) u16 Bs[3 * 8192];
  __shared__ alignas(16) float mnS[3 * 64];
  int bid = blockIdx.x, tid = threadIdx.x;
  if (bid & 1) score_body<128, 8>(qf2, m2t, mn2, kp2, bid >> 1, Bs, mnS, tid);
  else         score_body<256, 8>(qf3, m3t, mn3, kp3, bid >> 1, Bs, mnS, tid);
}

// ================= fused mid: q row-norms + Mahalanobis =================
template<int C>
DEV void rownorm_dev(const u16* __restrict__ x, float* __restrict__ out, int bid, int tid) {
  int row = bid * 4 + (tid >> 6);
  int lane = tid & 63;
  constexpr int E = C / 64;
  const u16* p = x + (size_t)row * C + lane * E;
  float s = 0.f;
#pragma unroll
  for (int i = 0; i < E; ++i) { float v = bf2f(p[i]); s += v * v; }
#pragma unroll
  for (int m = 1; m < 64; m <<= 1) s += __shfl_xor(s, m);
  if (lane == 0) out[row] = s;
}

template<int C>
DEV void maha_dev(const u16* __restrict__ qfb, const float* __restrict__ mu,
                  const u16* __restrict__ icovb, float* __restrict__ mh,
                  u16* As, float* muS, int bid, int tid) {
  constexpr int QT = 64, KCH = C / 8;
  int wave = tid >> 6, lane = tid & 63;
  int row0 = bid * QT;

  for (int i = tid; i < C; i += 256) muS[i] = mu[i];
  __syncthreads();
  for (int u = tid; u < QT * KCH; u += 256) {
    int r = u / KCH, cc = u % KCH;
    bf8v v = *(const bf8v*)(qfb + (size_t)(row0 + r) * C + cc * 8);
    s8v d;
#pragma unroll
    for (int i = 0; i < 8; ++i) d[i] = (short)f2bf((float)v[i] - muS[cc * 8 + i]);
    *(s8v*)(As + r * C + ((cc ^ (r & 7)) << 3)) = d;
  }
  __syncthreads();

  int arow = wave * 16 + (lane & 15);
  int kb = lane >> 4;
  float mm[4] = {0.f, 0.f, 0.f, 0.f};
#pragma unroll
  for (int cb = 0; cb < C / 16; ++cb) {
    f4v acc = (f4v){0.f, 0.f, 0.f, 0.f};
    int bcol = cb * 16 + (lane & 15);
#pragma unroll
    for (int kk = 0; kk < C / 32; ++kk) {
      int kc = kk * 4 + kb;
      bf8v a = *(const bf8v*)(As + arow * C + ((kc ^ (arow & 7)) << 3));
      bf8v b = *(const bf8v*)(icovb + (size_t)bcol * C + kc * 8);
      acc = __builtin_amdgcn_mfma_f32_16x16x32_bf16(a, b, acc, 0, 0, 0);
    }
#pragma unroll
    for (int r = 0; r < 4; ++r) {
      int row = wave * 16 + (lane >> 4) * 4 + r;
      int col = cb * 16 + (lane & 15);
      float dv = bf2f(As[row * C + (((col >> 3) ^ (row & 7)) << 3) + (col & 7)]);
      mm[r] += acc[r] * dv;
    }
  }
#pragma unroll
  for (int r = 0; r < 4; ++r) {
    float v = mm[r];
    v += __shfl_xor(v, 1); v += __shfl_xor(v, 2);
    v += __shfl_xor(v, 4); v += __shfl_xor(v, 8);
    if ((lane & 15) == 0)
      mh[row0 + wave * 16 + (lane >> 4) * 4 + r] = sqrtf(fmaxf(v, EPSF));
  }
}

__global__ __launch_bounds__(256) void k_mid(
    const u16* __restrict__ qf2b, const u16* __restrict__ qf3b,
    const float* __restrict__ mean2, const float* __restrict__ mean3,
    const u16* __restrict__ ic2b, const u16* __restrict__ ic3b,
    float* __restrict__ qn2, float* __restrict__ qn3,
    float* __restrict__ mh2, float* __restrict__ mh3) {
  __shared__ alignas(16) u16 As[64 * 256];
  __shared__ float muS[256];
  int bid = blockIdx.x, tid = threadIdx.x;
  if (bid < 3136)       rownorm_dev<128>(qf2b, qn2, bid, tid);
  else if (bid < 6272)  rownorm_dev<256>(qf3b, qn3, bid - 3136, tid);
  else if (bid < 6468)  maha_dev<128>(qf2b, mean2, ic2b, mh2, As, muS, bid - 6272, tid);
  else                  maha_dev<256>(qf3b, mean3, ic3b, mh3, As, muS, bid - 6468, tid);
}

// ================= combine: merge knn splits (+qn), build maps =================
template<int S>
DEV float knn_merge(const float* kp, int n, float qv) {
  float t0 = 1e30f, t1 = 1e30f, t2 = 1e30f, t3 = 1e30f, t4 = 1e30f;
  const float* p = kp + (size_t)n * S * 5;
#pragma unroll
  for (int i = 0; i < S * 5; ++i) ins5(p[i], t0, t1, t2, t3, t4);
  return 0.2f * (sqrtf(fmaxf(t0 + qv, EPSF)) + sqrtf(fmaxf(t1 + qv, EPSF)) +
                 sqrtf(fmaxf(t2 + qv, EPSF)) + sqrtf(fmaxf(t3 + qv, EPSF)) +
                 sqrtf(fmaxf(t4 + qv, EPSF)));
}

__global__ __launch_bounds__(256) void k_combine(
    const float* __restrict__ kp2, const float* __restrict__ kp3,
    const float* __restrict__ qn2, const float* __restrict__ qn3,
    const float* __restrict__ mh2, const float* __restrict__ mh3,
    float* __restrict__ out) {
  int n = blockIdx.x * 256 + threadIdx.x;
  float m2v = 0.5f * (knn_merge<8>(kp2, n, qn2[n]) + mh2[n]);
  float m3v = 0.5f * (knn_merge<8>(kp3, n, qn3[n]) + mh3[n]);
  out[16 + n] = 0.5f * (m2v + m3v);
  out[16 + NQ + n] = m2v;
  out[16 + 2 * NQ + n] = m3v;
}

// ================= per-image top-10 mean over 784-pixel map =================
__global__ __launch_bounds__(256) void k_top10(const float* __restrict__ comb, float* __restrict__ pred) {
  __shared__ float vals[1024];
  __shared__ float rv[256];
  __shared__ int ri[256];
  __shared__ float ssum;
  int b = blockIdx.x, tid = threadIdx.x;
  for (int i = tid; i < 1024; i += 256) vals[i] = (i < PP) ? comb[b * PP + i] : -1e30f;
  if (tid == 0) ssum = 0.f;
  __syncthreads();
  for (int it = 0; it < 10; ++it) {
    float bv = -1e30f; int bi = 0;
    for (int i = tid; i < 1024; i += 256) { float v = vals[i]; if (v > bv) { bv = v; bi = i; } }
    rv[tid] = bv; ri[tid] = bi;
    __syncthreads();
    for (int s = 128; s; s >>= 1) {
      if (tid < s && rv[tid + s] > rv[tid]) { rv[tid] = rv[tid + s]; ri[tid] = ri[tid + s]; }
      __syncthreads();
    }
    if (tid == 0) { ssum += rv[0]; vals[ri[0]] = -1e30f; }
    __syncthreads();
  }
  if (tid == 0) pred[b] = ssum * 0.1f;
}

extern "C" void kernel_launch(void* const* d_in, const int* in_sizes, int n_in,
                              void* d_out, int out_size, void* d_ws, size_t ws_size,
                              hipStream_t stream) {
  const float* q2    = (const float*)d_in[0];
  const float* q3    = (const float*)d_in[1];
  const float* mem2  = (const float*)d_in[2];
  const float* mem3  = (const float*)d_in[3];
  const float* mean2 = (const float*)d_in[4];
  const float* mean3 = (const float*)d_in[5];
  const float* icov2 = (const float*)d_in[6];
  const float* icov3 = (const float*)d_in[7];
  float* out = (float*)d_out;

  char* w = (char*)d_ws;
  auto alloc = [&](size_t bytes) { void* p = (void*)w; w += (bytes + 255) & ~(size_t)255; return p; };
  u16* qf2b = (u16*)alloc((size_t)NQ * 128 * 2);
  u16* qf3b = (u16*)alloc((size_t)NQ * 256 * 2);
  u16* m2t  = (u16*)alloc((size_t)MM * 128 * 2);
  u16* m3t  = (u16*)alloc((size_t)MM * 256 * 2);
  u16* ic2b = (u16*)alloc((size_t)128 * 128 * 2);
  u16* ic3b = (u16*)alloc((size_t)256 * 256 * 2);
  float* qn2 = (float*)alloc((size_t)NQ * 4);
  float* qn3 = (float*)alloc((size_t)NQ * 4);
  float* mn2 = (float*)alloc((size_t)MM * 4);
  float* mn3 = (float*)alloc((size_t)MM * 4);
  float* kp2 = (float*)alloc((size_t)NQ * 8 * 5 * 4);
  float* kp3 = (float*)alloc((size_t)NQ * 8 * 5 * 4);
  float* mh2 = (float*)alloc((size_t)NQ * 4);
  float* mh3 = (float*)alloc((size_t)NQ * 4);

  k_prep<<<6488, 256, 0, stream>>>(q2, q3, mem2, mem3, icov2, icov3,
                                   qf2b, qf3b, m2t, m3t, ic2b, ic3b, mn2, mn3);

  // fused score: 392 C=256 blocks (even bid) + 392 C=128 blocks (odd bid)
  k_score_f<<<784, 512, 0, stream>>>(qf3b, m3t, mn3, kp3, qf2b, m2t, mn2, kp2);

  k_mid<<<6664, 256, 0, stream>>>(qf2b, qf3b, mean2, mean3, ic2b, ic3b, qn2, qn3, mh2, mh3);

  k_combine<<<NQ / 256, 256, 0, stream>>>(kp2, kp3, qn2, qn3, mh2, mh3, out);
  k_top10<<<16, 256, 0, stream>>>(out + 16, out);

  (void)in_sizes; (void)n_in; (void)out_size; (void)ws_size;
}